// Round 8
// baseline (12694.053 us; speedup 1.0000x reference)
//
#include <hip/hip_runtime.h>
#include <hip/hip_bf16.h>
#include <math.h>

constexpr int Bz = 1024;
constexpr int C0 = 271;   // input channels
constexpr int CP0 = 288;  // padded to 9*32
constexpr int Tt = 281;   // time
constexpr int TR = 292;   // padded rows per batch: row = t+1; rows 0,282..291 zero
constexpr int H1 = 128;
constexpr int H2 = 256;
constexpr int NCLS = 1854;
constexpr int ED = 16;
constexpr float BN_INV = 0.9999950000374996f;  // 1/sqrt(1+1e-5)

typedef __attribute__((ext_vector_type(8))) short s16x8;
typedef __attribute__((ext_vector_type(16))) float f32x16;

// fast erf (Abramowitz-Stegun 7.1.26, |eps| < 1.5e-7) -- ~11 VALU ops vs ~35 for libm erff
__device__ __forceinline__ float erf_fast(float x) {
    float ax = fabsf(x);
    float t = __builtin_amdgcn_rcpf(fmaf(0.3275911f, ax, 1.0f));
    float p = fmaf(1.061405429f, t, -1.453152027f);
    p = fmaf(p, t, 1.421413741f);
    p = fmaf(p, t, -0.284496736f);
    p = fmaf(p, t, 0.254829592f);
    float e = __expf(-ax * ax);
    float r = fmaf(-p * t, e, 1.0f);
    return copysignf(r, x);
}
__device__ __forceinline__ float gelu_f(float v) {
    return 0.5f * v * (1.0f + erf_fast(v * 0.7071067811865475f));
}
__device__ __forceinline__ float bf2f(short s) {
    return __builtin_bit_cast(float, ((unsigned int)(unsigned short)s) << 16);
}
__device__ __forceinline__ short f2bf(float f) {
    return __builtin_bit_cast(short, __float2bfloat16(f));
}

typedef unsigned int u32;
typedef const __attribute__((address_space(1))) u32 gu32;
typedef __attribute__((address_space(3))) u32 lu32;

__device__ __forceinline__ void gl16(const void* g, void* l) {
    __builtin_amdgcn_global_load_lds((gu32*)(uintptr_t)g, (lu32*)(uintptr_t)l, 16, 0, 0);
}
template<int N> __device__ __forceinline__ void waitv() {
    asm volatile("s_waitcnt vmcnt(%0)" :: "i"(N) : "memory");
}
__device__ __forceinline__ void hard_barrier() {
    __builtin_amdgcn_sched_barrier(0);
    __builtin_amdgcn_s_barrier();
    __builtin_amdgcn_sched_barrier(0);
}

// ---------------- prep kernels ----------------

__global__ void zrows_k(short* base, int C) {
    const int b = blockIdx.x;
    const int n = 11 * (C / 8);
    for (int i = threadIdx.x; i < n; i += 256) {
        int ri = i / (C / 8), c8 = i - ri * (C / 8);
        int row = (ri == 0) ? 0 : 281 + ri;   // 0, 282..291
        *(int4*)(base + ((size_t)b * TR + row) * C + c8 * 8) = make_int4(0, 0, 0, 0);
    }
}

__global__ void softmax_rows_k(const float* __restrict__ a, float* __restrict__ o, int n) {
    __shared__ float red[256];
    const int row = blockIdx.x, tid = threadIdx.x;
    const float* r = a + (size_t)row * n;
    float m = -1e30f;
    for (int i = tid; i < n; i += 256) m = fmaxf(m, r[i]);
    red[tid] = m; __syncthreads();
    for (int s = 128; s > 0; s >>= 1) { if (tid < s) red[tid] = fmaxf(red[tid], red[tid + s]); __syncthreads(); }
    m = red[0]; __syncthreads();
    float acc = 0.f;
    for (int i = tid; i < n; i += 256) acc += expf(r[i] - m);
    red[tid] = acc; __syncthreads();
    for (int s = 128; s > 0; s >>= 1) { if (tid < s) red[tid] += red[tid + s]; __syncthreads(); }
    const float inv = 1.0f / red[0];
    for (int i = tid; i < n; i += 256) o[(size_t)row * n + i] = expf(r[i] - m) * inv;
}

__global__ void gemm_M_k(const float* __restrict__ sa_w, const float* __restrict__ attnS,
                         float* __restrict__ M) {
    int idx = blockIdx.x * 256 + threadIdx.x;
    if (idx >= H1 * C0) return;
    int o = idx / C0, c = idx - o * C0;
    float s = 0.f;
    for (int i = 0; i < C0; ++i) s = fmaf(sa_w[(size_t)o * C0 + i], attnS[(size_t)i * C0 + c], s);
    M[idx] = s;
}

// fragment-order weights: chunk ((cc*K+k)*OB32 + ob)*2 + kk; lane holds o=ob*32+(l&31),
// c = cc*32 + kk*16 + (l>>5)*8 + j
__global__ void wfrag_k(const float* __restrict__ w, short* __restrict__ out,
                        int CIN, int O, int K, int NC) {
    int idx = blockIdx.x * 256 + threadIdx.x;
    int OB32 = O / 32;
    int total = NC * K * OB32 * 2 * 512;
    if (idx >= total) return;
    int j = idx & 7, lane = (idx >> 3) & 63, kk = (idx >> 9) & 1, r = idx >> 10;
    int ob = r % OB32, r2 = r / OB32;
    int k = r2 % K, cc = r2 / K;
    int o = ob * 32 + (lane & 31);
    int c = cc * 32 + kk * 16 + (lane >> 5) * 8 + j;
    float v = (c < CIN) ? w[((size_t)o * CIN + c) * K + k] : 0.f;
    out[idx] = f2bf(v);
}

// stage-A fused weights, fragment order, NC=10: sum_h subj_w[s][o][h]*M[h][c]
__global__ void msubA_k(const float* __restrict__ subj_w, const float* __restrict__ M,
                        short* __restrict__ out) {
    int idx = blockIdx.x * 256 + threadIdx.x;
    const int per_s = 10 * 1 * 4 * 2 * 512;
    if (idx >= 4 * per_s) return;
    int s = idx / per_s, rem = idx % per_s;
    int j = rem & 7, lane = (rem >> 3) & 63, kk = (rem >> 9) & 1, r = rem >> 10;
    int ob = r % 4, cc = r / 4;
    int o = ob * 32 + (lane & 31);
    int c = cc * 32 + kk * 16 + (lane >> 5) * 8 + j;
    float a = 0.f;
    if (c < C0) {
        const float* wr = subj_w + ((size_t)s * 128 + o) * 128;
        for (int h = 0; h < 128; ++h) a = fmaf(wr[h], M[(size_t)h * C0 + c], a);
    }
    out[idx] = f2bf(a);
}

__global__ void biasS_k(const float* __restrict__ subj_w, const float* __restrict__ sa_b,
                        const float* __restrict__ subj_b, float* __restrict__ biasS) {
    int idx = blockIdx.x * 256 + threadIdx.x;
    if (idx >= 4 * H1) return;
    int s = idx >> 7, o = idx & 127;
    const float* wr = subj_w + ((size_t)s * H1 + o) * H1;
    float a = subj_b[idx];
    for (int h = 0; h < H1; ++h) a = fmaf(wr[h], sa_b[h], a);
    biasS[idx] = a;
}

// X [b][c][t] fp32 -> xT [b][row=t+1][288] bf16
__global__ void xpose_k(const float* __restrict__ X, short* __restrict__ xT) {
    __shared__ float tile[32][33];
    int b = blockIdx.z;
    int t0 = blockIdx.x * 32, c0 = blockIdx.y * 32;
    int tx = threadIdx.x, ty = threadIdx.y;
    #pragma unroll
    for (int i = 0; i < 4; ++i) {
        int c = c0 + ty + i * 8, t = t0 + tx;
        float v = 0.f;
        if (c < C0 && t < Tt) v = X[((size_t)b * C0 + c) * Tt + t];
        tile[ty + i * 8][tx] = v;
    }
    __syncthreads();
    #pragma unroll
    for (int i = 0; i < 4; ++i) {
        int t = t0 + ty + i * 8, c = c0 + tx;
        if (t < Tt) xT[((size_t)b * TR + t + 1) * CP0 + c] = f2bf(tile[tx][ty + i * 8]);
    }
}

// ---------------- ring/whole-X conv kernel: 80KB LDS -> 2 blocks/CU ----------------
// Full-T, NB=1, 8 waves. 256ch: ring-2 of 40KB cc-pair slices, counted-vmcnt phases
// (A-loads issued BEFORE next slice's gl16s so FIFO vmcnt keeps prefetch in flight).
// 128ch: whole-X 80KB slab, single stage, barrier-free K-loop. NTH=2 splits t-range
// between wave pairs when O_BLK=128 (4 o-slices).

constexpr int SLICEB = 40960;   // 320 rows * 128 B

template<int K, int NCC, int NCU, int O_BLK, int NTH, bool RING,
         bool GELU, bool HASRES, bool POOL>
__global__ __launch_bounds__(512, 4)
void convRK(const short* __restrict__ xin, int XC,
            const short* __restrict__ wf,
            const float* __restrict__ bias,
            const float* __restrict__ gamma, const float* __restrict__ beta,
            const short* __restrict__ res, short* __restrict__ outp,
            float* __restrict__ pooled,
            const int* __restrict__ sidx, int wsub, int bsub)
{
    constexpr int OB32 = O_BLK / 32;
    constexpr int NTS  = (NTH == 2) ? 5 : 9;
    constexpr int ROFF = 1 - (K - 1) / 2;
    constexpr int O2   = O_BLK * 2;
    constexpr int RCH  = O_BLK / 8;
    constexpr int APL  = 2 * K * 2;            // A loads per ring pair per wave
    constexpr int SECTS = (81920 / (32 * O2)) < 9 ? (81920 / (32 * O2)) : 9;
    constexpr int NSEC  = (9 + SECTS - 1) / SECTS;

    __shared__ __align__(16) char smem[81920];

    const int b    = blockIdx.x;
    const int tid  = threadIdx.x;
    const int lane = tid & 63, w = tid >> 6;
    const int l31  = lane & 31, hi = lane >> 5;
    const int wvo  = (NTH == 2) ? (w & (OB32 - 1)) : w;
    const int th   = (NTH == 2) ? (w >> 2) : 0;
    const int TS0  = (NTH == 2) ? th * 5 : 0;

    int subj = sidx ? sidx[b] : 0;
    const short* wb = wf + (size_t)subj * wsub;
    const float* bb = bias + (size_t)subj * bsub;

    f32x16 acc[NTS];
    #pragma unroll
    for (int i = 0; i < NTS; ++i)
        #pragma unroll
        for (int e = 0; e < 16; ++e) acc[i][e] = 0.f;

    if constexpr (RING) {
        constexpr int NPAIR = NCC / 2;
        auto issueSlice = [&](int s, int bi) {
            #pragma unroll
            for (int q = 0; q < 5; ++q) {
                int c = q * 8 + w;
                int pos = c * 1024 + lane * 16;
                int r = pos >> 7;
                int up = (pos >> 4) & 7;
                int us = up ^ (r & 7);
                int rr = r > 291 ? 291 : r;
                gl16(xin + ((size_t)b * TR + rr) * XC + (s * 8 + us) * 8,
                     smem + bi * SLICEB + c * 1024);
            }
        };
        issueSlice(0, 0);
        #pragma unroll
        for (int p = 0; p < NPAIR; ++p) {
            s16x8 a[2][K][2];
            #pragma unroll
            for (int cj = 0; cj < 2; ++cj)
                #pragma unroll
                for (int k = 0; k < K; ++k)
                    #pragma unroll
                    for (int kk = 0; kk < 2; ++kk) {
                        int ci = (((2 * p + cj) * K + k) * OB32 + wvo) * 2 + kk;
                        a[cj][k][kk] = *(const s16x8*)(wb + (size_t)ci * 512 + lane * 8);
                    }
            __builtin_amdgcn_sched_barrier(0);
            if (p + 1 < NPAIR) issueSlice(p + 1, (p + 1) & 1);
            __builtin_amdgcn_sched_barrier(0);
            if (p + 1 < NPAIR) waitv<APL + 5>(); else waitv<APL>();
            hard_barrier();
            const char* Xb = smem + (p & 1) * SLICEB;
            __builtin_amdgcn_s_setprio(1);
            #pragma unroll
            for (int cj = 0; cj < 2; ++cj)
                #pragma unroll
                for (int k = 0; k < K; ++k)
                    #pragma unroll
                    for (int kk = 0; kk < 2; ++kk)
                        #pragma unroll
                        for (int t = 0; t < NTS; ++t) {
                            int ts = TS0 + t;
                            if (ts < 9) {
                                int rl = ts * 32 + l31 + k + ROFF;
                                s16x8 bv = *(const s16x8*)(Xb + rl * 128 +
                                    (((cj * 4 + kk * 2 + hi) ^ (rl & 7)) << 4));
                                acc[t] = __builtin_amdgcn_mfma_f32_32x32x16_bf16(
                                    a[cj][k][kk], bv, acc[t], 0, 0, 0);
                            }
                        }
            __builtin_amdgcn_s_setprio(0);
            hard_barrier();
        }
    } else {
        constexpr int ROWB = NCU * 64;
        constexpr int CHW  = 20 * NCU;         // 320*ROWB/1024
        #pragma unroll
        for (int q = 0; q < CHW / 8; ++q) {
            int c = q * 8 + w;
            int pos = c * 1024 + lane * 16;
            int r = pos / ROWB;
            int up = (pos >> 4) & (2 * NCU - 1);
            int us = up ^ (r & 7);
            int rr = r > 291 ? 291 : r;
            gl16(xin + ((size_t)b * TR + rr) * XC + us * 8, smem + c * 1024);
        }
        waitv<0>();
        hard_barrier();
        #pragma unroll
        for (int cc = 0; cc < NCC; ++cc) {
            s16x8 a[K][2];
            #pragma unroll
            for (int k = 0; k < K; ++k)
                #pragma unroll
                for (int kk = 0; kk < 2; ++kk) {
                    int ci = ((cc * K + k) * OB32 + wvo) * 2 + kk;
                    a[k][kk] = *(const s16x8*)(wb + (size_t)ci * 512 + lane * 8);
                }
            __builtin_amdgcn_s_setprio(1);
            #pragma unroll
            for (int k = 0; k < K; ++k)
                #pragma unroll
                for (int kk = 0; kk < 2; ++kk)
                    #pragma unroll
                    for (int t = 0; t < NTS; ++t) {
                        int ts = TS0 + t;
                        if (ts < 9) {
                            int rl = ts * 32 + l31 + k + ROFF;
                            s16x8 bv = *(const s16x8*)(smem + rl * ROWB +
                                (((cc * 4 + kk * 2 + hi) ^ (rl & 7)) << 4));
                            acc[t] = __builtin_amdgcn_mfma_f32_32x32x16_bf16(
                                a[k][kk], bv, acc[t], 0, 0, 0);
                        }
                    }
            __builtin_amdgcn_s_setprio(0);
        }
    }

    // ---- epilogue: sectioned LDS staging, coalesced stores (res+gelu in copy) ----
    float ps[8];
    if constexpr (POOL) {
        #pragma unroll
        for (int j = 0; j < 8; ++j) ps[j] = 0.f;
    }

    for (int g = 0; g < NSEC; ++g) {
        hard_barrier();
        #pragma unroll
        for (int t = 0; t < NTS; ++t) {
            int ts = TS0 + t;
            if (ts < 9 && ts >= g * SECTS && ts < (g + 1) * SECTS) {
                #pragma unroll
                for (int rq = 0; rq < 4; ++rq)
                    #pragma unroll
                    for (int rp = 0; rp < 2; ++rp) {
                        const int oc = wvo * 32 + 8 * rq + rp * 2 + 4 * hi;
                        const float bv0 = bb[oc], bv1 = bb[oc + 1];
                        const float g0 = gamma ? gamma[oc] * BN_INV : 1.f;
                        const float g1 = gamma ? gamma[oc + 1] * BN_INV : 1.f;
                        const float e0 = beta ? beta[oc] : 0.f;
                        const float e1 = beta ? beta[oc + 1] : 0.f;
                        const int r0 = rq * 4 + rp * 2;
                        float v0 = (acc[t][r0] + bv0) * g0 + e0;
                        float v1 = (acc[t][r0 + 1] + bv1) * g1 + e1;
                        int tl = ts * 32 + l31;
                        int rowsec = tl - g * SECTS * 32;
                        int byte = rowsec * O2 + ((oc * 2) ^ ((tl & 15) << 4));
                        __hip_bfloat162 pk;
                        pk.x = __float2bfloat16(v0);
                        pk.y = __float2bfloat16(v1);
                        *(__hip_bfloat162*)(smem + byte) = pk;
                    }
            }
        }
        hard_barrier();
        const int tsend = (g + 1) * SECTS < 9 ? (g + 1) * SECTS : 9;
        const int secrows = (tsend - g * SECTS) * 32;
        for (int q = tid; q < secrows * RCH; q += 512) {
            int rr = q / RCH, cp = q - rr * RCH;
            int tt = g * SECTS * 32 + rr;
            if (tt >= Tt) continue;
            s16x8 hv = *(const s16x8*)(smem + rr * O2 + ((cp * 16) ^ ((rr & 15) << 4)));
            size_t orow = ((size_t)b * TR + tt + 1) * O_BLK + cp * 8;
            s16x8 rv;
            if (HASRES) rv = *(const s16x8*)(res + orow);
            if constexpr (POOL) {
                #pragma unroll
                for (int j = 0; j < 8; ++j) {
                    float v = bf2f(hv[j]);
                    if (HASRES) v += bf2f(rv[j]);
                    if (GELU) v = gelu_f(v);
                    ps[j] += v;
                }
            } else {
                s16x8 ov;
                #pragma unroll
                for (int j = 0; j < 8; ++j) {
                    float v = bf2f(hv[j]);
                    if (HASRES) v += bf2f(rv[j]);
                    if (GELU) v = gelu_f(v);
                    ov[j] = f2bf(v);
                }
                *(s16x8*)(outp + orow) = ov;
            }
        }
    }

    if constexpr (POOL) {
        constexpr int NRED = 512 / RCH;
        float* part = (float*)smem;
        hard_barrier();
        #pragma unroll
        for (int j = 0; j < 8; ++j) part[tid * 8 + j] = ps[j];
        hard_barrier();
        if (tid < O_BLK) {
            int cp = tid >> 3, j = tid & 7;
            float s = 0.f;
            for (int r = 0; r < NRED; ++r) s += part[(cp + RCH * r) * 8 + j];
            pooled[(size_t)b * H2 + tid] = s * (1.0f / 281.0f);
        }
    }
}

// ---------------- head kernels ----------------

__global__ void head1_k(const float* __restrict__ pooled, const float* __restrict__ emb,
                        const int* __restrict__ sidx, const float* __restrict__ w1,
                        const float* __restrict__ b1, float* __restrict__ hout) {
    int idx = blockIdx.x * 256 + threadIdx.x;
    if (idx >= Bz * H1) return;
    int b = idx >> 7, j = idx & 127;
    const float* wr = w1 + (size_t)j * (H2 + ED);
    const float* pr = pooled + (size_t)b * H2;
    float a = b1[j];
    for (int i = 0; i < H2; ++i) a = fmaf(pr[i], wr[i], a);
    const float* er = emb + (size_t)sidx[b] * ED;
    #pragma unroll
    for (int e = 0; e < ED; ++e) a = fmaf(er[e], wr[H2 + e], a);
    hout[idx] = fmaxf(a, 0.f);
}

__global__ __launch_bounds__(256)
void head2_k(const float* __restrict__ h, const float* __restrict__ w2,
             const float* __restrict__ b2, float* __restrict__ out) {
    const int n0 = blockIdx.x * 64;
    const int b0 = blockIdx.y * 16;
    __shared__ float hs[16][128];
    __shared__ float w2s[64][129];
    const int tid = threadIdx.x;
    for (int idx = tid; idx < 16 * 128; idx += 256) {
        int bl = idx >> 7, j = idx & 127;
        hs[bl][j] = h[(size_t)(b0 + bl) * H1 + j];
    }
    for (int idx = tid; idx < 64 * 128; idx += 256) {
        int nl = idx >> 7, j = idx & 127;
        int n = n0 + nl;
        w2s[nl][j] = (n < NCLS) ? w2[(size_t)n * H1 + j] : 0.f;
    }
    __syncthreads();
    const int nl = tid & 63, bg = tid >> 6;
    float acc[4] = {0.f, 0.f, 0.f, 0.f};
    for (int j = 0; j < 128; ++j) {
        const float wv = w2s[nl][j];
        #pragma unroll
        for (int bb = 0; bb < 4; ++bb) acc[bb] = fmaf(wv, hs[bg * 4 + bb][j], acc[bb]);
    }
    const int n = n0 + nl;
    if (n < NCLS) {
        const float bv = b2[n];
        #pragma unroll
        for (int bb = 0; bb < 4; ++bb)
            out[(size_t)(b0 + bg * 4 + bb) * NCLS + n] = acc[bb] + bv;
    }
}

// ---------------- host launch ----------------

extern "C" void kernel_launch(void* const* d_in, const int* in_sizes, int n_in,
                              void* d_out, int out_size, void* d_ws, size_t ws_size,
                              hipStream_t stream) {
    const float* X      = (const float*)d_in[0];
    const int*   sidx   = (const int*)  d_in[1];
    const float* attn   = (const float*)d_in[2];
    const float* sa_w   = (const float*)d_in[3];
    const float* sa_b   = (const float*)d_in[4];
    const float* subj_w = (const float*)d_in[5];
    const float* subj_b = (const float*)d_in[6];
    const float* b1c1w = (const float*)d_in[7];  const float* b1c1b = (const float*)d_in[8];
    const float* b1c2w = (const float*)d_in[9];  const float* b1c2b = (const float*)d_in[10];
    const float* b1g1  = (const float*)d_in[11]; const float* b1be1 = (const float*)d_in[12];
    const float* b1g2  = (const float*)d_in[13]; const float* b1be2 = (const float*)d_in[14];
    const float* b2c1w = (const float*)d_in[15]; const float* b2c1b = (const float*)d_in[16];
    const float* b2c2w = (const float*)d_in[17]; const float* b2c2b = (const float*)d_in[18];
    const float* b2g1  = (const float*)d_in[19]; const float* b2be1 = (const float*)d_in[20];
    const float* b2g2  = (const float*)d_in[21]; const float* b2be2 = (const float*)d_in[22];
    const float* b2skw = (const float*)d_in[23]; const float* b2skb = (const float*)d_in[24];
    const float* b3c1w = (const float*)d_in[25]; const float* b3c1b = (const float*)d_in[26];
    const float* b3c2w = (const float*)d_in[27]; const float* b3c2b = (const float*)d_in[28];
    const float* b3g1  = (const float*)d_in[29]; const float* b3be1 = (const float*)d_in[30];
    const float* b3g2  = (const float*)d_in[31]; const float* b3be2 = (const float*)d_in[32];
    const float* emb   = (const float*)d_in[33];
    const float* hw1   = (const float*)d_in[34]; const float* hb1 = (const float*)d_in[35];
    const float* hw2   = (const float*)d_in[36]; const float* hb2 = (const float*)d_in[37];
    float* out = (float*)d_out;
    (void)in_sizes; (void)n_in; (void)out_size; (void)ws_size;

    char* wsp = (char*)d_ws;
    size_t off = 0;
    auto allocF = [&](size_t n) {
        float* p = (float*)(wsp + off);
        off += ((n * sizeof(float)) + 255) & ~(size_t)255;
        return p;
    };
    auto allocS = [&](size_t n) {
        short* p = (short*)(wsp + off);
        off += ((n * sizeof(short)) + 255) & ~(size_t)255;
        return p;
    };
    float* attnS   = allocF((size_t)C0 * C0);
    float* Mmat    = allocF((size_t)H1 * C0);
    float* biasS   = allocF((size_t)4 * H1);
    float* pooled  = allocF((size_t)Bz * H2);
    float* hbuf    = allocF((size_t)Bz * H1);
    short* wStageA = allocS((size_t)4 * 10 * 4 * 2 * 512);    // per-subj 40960 (NC=10)
    short* wp_b1c1 = allocS((size_t)4 * 3 * 4 * 2 * 512);
    short* wp_b1c2 = allocS((size_t)4 * 3 * 4 * 2 * 512);
    short* wp_skip = allocS((size_t)4 * 1 * 8 * 2 * 512);
    short* wp_b2c1 = allocS((size_t)4 * 3 * 8 * 2 * 512);
    short* wp_b2c2 = allocS((size_t)8 * 3 * 8 * 2 * 512);
    short* wp_b3c1 = allocS((size_t)8 * 3 * 8 * 2 * 512);
    short* wp_b3c2 = allocS((size_t)8 * 3 * 8 * 2 * 512);
    short* xT   = allocS((size_t)Bz * TR * CP0 + 64);   // +64 pad: unit 36..39 over-read guard
    short* bufP = allocS((size_t)Bz * TR * H1);
    short* bufQ = allocS((size_t)Bz * TR * H1);
    short* bufR = allocS((size_t)Bz * TR * H2);
    short* bufS = allocS((size_t)Bz * TR * H2);

    // ---- zero margin rows ----
    zrows_k<<<Bz, 256, 0, stream>>>(xT, CP0);
    zrows_k<<<Bz, 256, 0, stream>>>(bufP, H1);
    zrows_k<<<Bz, 256, 0, stream>>>(bufQ, H1);
    zrows_k<<<Bz, 256, 0, stream>>>(bufR, H2);
    zrows_k<<<Bz, 256, 0, stream>>>(bufS, H2);

    // ---- prep ----
    softmax_rows_k<<<C0, 256, 0, stream>>>(attn, attnS, C0);
    gemm_M_k<<<(H1 * C0 + 255) / 256, 256, 0, stream>>>(sa_w, attnS, Mmat);
    msubA_k<<<(4 * 40960 + 255) / 256, 256, 0, stream>>>(subj_w, Mmat, wStageA);
    biasS_k<<<2, 256, 0, stream>>>(subj_w, sa_b, subj_b, biasS);
    wfrag_k<<<(4*3*4*2*512 + 255) / 256, 256, 0, stream>>>(b1c1w, wp_b1c1, 128, 128, 3, 4);
    wfrag_k<<<(4*3*4*2*512 + 255) / 256, 256, 0, stream>>>(b1c2w, wp_b1c2, 128, 128, 3, 4);
    wfrag_k<<<(4*1*8*2*512 + 255) / 256, 256, 0, stream>>>(b2skw, wp_skip, 128, 256, 1, 4);
    wfrag_k<<<(4*3*8*2*512 + 255) / 256, 256, 0, stream>>>(b2c1w, wp_b2c1, 128, 256, 3, 4);
    wfrag_k<<<(8*3*8*2*512 + 255) / 256, 256, 0, stream>>>(b2c2w, wp_b2c2, 256, 256, 3, 8);
    wfrag_k<<<(8*3*8*2*512 + 255) / 256, 256, 0, stream>>>(b3c1w, wp_b3c1, 256, 256, 3, 8);
    wfrag_k<<<(8*3*8*2*512 + 255) / 256, 256, 0, stream>>>(b3c2w, wp_b3c2, 256, 256, 3, 8);
    xpose_k<<<dim3(9, 9, Bz), dim3(32, 8), 0, stream>>>(X, xT);

    // ---- conv stack: <K, NCC, NCU, O_BLK, NTH, RING, GELU, HASRES, POOL> ----
    // stageA: xT(288ch, NCC=10 ring) -> P(128)
    convRK<1, 10, 10, 128, 2, true, false, false, false><<<Bz, 512, 0, stream>>>(
        xT, CP0, wStageA, biasS, nullptr, nullptr, nullptr, bufP, nullptr, sidx, 40960, 128);
    // block1: P -> Q (gelu+bn); Q (+res P) -> P in-place  (whole-X 128ch)
    convRK<3, 4, 4, 128, 2, false, true, false, false><<<Bz, 512, 0, stream>>>(
        bufP, H1, wp_b1c1, b1c1b, b1g1, b1be1, nullptr, bufQ, nullptr, nullptr, 0, 0);
    convRK<3, 4, 4, 128, 2, false, true, true, false><<<Bz, 512, 0, stream>>>(
        bufQ, H1, wp_b1c2, b1c2b, b1g2, b1be2, bufP, bufP, nullptr, nullptr, 0, 0);
    // block2: skip P->S; c1 P->R; c2 R(+res S)->S in-place
    convRK<1, 4, 4, 256, 1, false, false, false, false><<<Bz, 512, 0, stream>>>(
        bufP, H1, wp_skip, b2skb, nullptr, nullptr, nullptr, bufS, nullptr, nullptr, 0, 0);
    convRK<3, 4, 4, 256, 1, false, true, false, false><<<Bz, 512, 0, stream>>>(
        bufP, H1, wp_b2c1, b2c1b, b2g1, b2be1, nullptr, bufR, nullptr, nullptr, 0, 0);
    convRK<3, 8, 8, 256, 1, true, true, true, false><<<Bz, 512, 0, stream>>>(
        bufR, H2, wp_b2c2, b2c2b, b2g2, b2be2, bufS, bufS, nullptr, nullptr, 0, 0);
    // block3: c1 S->R; c2 R(+res S) -> fused global-avg-pool (direct store)
    convRK<3, 8, 8, 256, 1, true, true, false, false><<<Bz, 512, 0, stream>>>(
        bufS, H2, wp_b3c1, b3c1b, b3g1, b3be1, nullptr, bufR, nullptr, nullptr, 0, 0);
    convRK<3, 8, 8, 256, 1, true, true, true, true><<<Bz, 512, 0, stream>>>(
        bufR, H2, wp_b3c2, b3c2b, b3g2, b3be2, bufS, nullptr, pooled, nullptr, 0, 0);

    // ---- head ----
    head1_k<<<(Bz * H1 + 255) / 256, 256, 0, stream>>>(pooled, emb, sidx, hw1, hb1, hbuf);
    head2_k<<<dim3((NCLS + 63) / 64, Bz / 16), 256, 0, stream>>>(hbuf, hw2, hb2, out);
}

// Round 9
// 1673.492 us; speedup vs baseline: 7.5854x; 7.5854x over previous
//
#include <hip/hip_runtime.h>
#include <hip/hip_bf16.h>
#include <math.h>

constexpr int Bz = 1024;
constexpr int C0 = 271;   // input channels
constexpr int CP0 = 288;  // padded to 9*32
constexpr int Tt = 281;   // time
constexpr int TR = 292;   // padded rows per batch: row = t+1; rows 0,282..291 zero
constexpr int H1 = 128;
constexpr int H2 = 256;
constexpr int NCLS = 1854;
constexpr int ED = 16;
constexpr float BN_INV = 0.9999950000374996f;  // 1/sqrt(1+1e-5)

typedef __attribute__((ext_vector_type(8))) short s16x8;
typedef __attribute__((ext_vector_type(16))) float f32x16;

// fast erf (Abramowitz-Stegun 7.1.26, |eps| < 1.5e-7)
__device__ __forceinline__ float erf_fast(float x) {
    float ax = fabsf(x);
    float t = __builtin_amdgcn_rcpf(fmaf(0.3275911f, ax, 1.0f));
    float p = fmaf(1.061405429f, t, -1.453152027f);
    p = fmaf(p, t, 1.421413741f);
    p = fmaf(p, t, -0.284496736f);
    p = fmaf(p, t, 0.254829592f);
    float e = __expf(-ax * ax);
    float r = fmaf(-p * t, e, 1.0f);
    return copysignf(r, x);
}
__device__ __forceinline__ float gelu_f(float v) {
    return 0.5f * v * (1.0f + erf_fast(v * 0.7071067811865475f));
}
__device__ __forceinline__ float bf2f(short s) {
    return __builtin_bit_cast(float, ((unsigned int)(unsigned short)s) << 16);
}
__device__ __forceinline__ short f2bf(float f) {
    return __builtin_bit_cast(short, __float2bfloat16(f));
}

typedef unsigned int u32;
typedef const __attribute__((address_space(1))) u32 gu32;
typedef __attribute__((address_space(3))) u32 lu32;

__device__ __forceinline__ void gl16(const void* g, void* l) {
    __builtin_amdgcn_global_load_lds((gu32*)(uintptr_t)g, (lu32*)(uintptr_t)l, 16, 0, 0);
}
template<int N> __device__ __forceinline__ void waitv() {
    asm volatile("s_waitcnt vmcnt(%0)" :: "i"(N) : "memory");
}
__device__ __forceinline__ void hard_barrier() {
    __builtin_amdgcn_sched_barrier(0);
    __builtin_amdgcn_s_barrier();
    __builtin_amdgcn_sched_barrier(0);
}

// ---------------- prep kernels ----------------

__global__ void zrows_k(short* base, int C) {
    const int b = blockIdx.x;
    const int n = 11 * (C / 8);
    for (int i = threadIdx.x; i < n; i += 256) {
        int ri = i / (C / 8), c8 = i - ri * (C / 8);
        int row = (ri == 0) ? 0 : 281 + ri;   // 0, 282..291
        *(int4*)(base + ((size_t)b * TR + row) * C + c8 * 8) = make_int4(0, 0, 0, 0);
    }
}

__global__ void zerof_k(float* p, int n) {
    int i = blockIdx.x * 256 + threadIdx.x;
    if (i < n) p[i] = 0.f;
}

__global__ void softmax_rows_k(const float* __restrict__ a, float* __restrict__ o, int n) {
    __shared__ float red[256];
    const int row = blockIdx.x, tid = threadIdx.x;
    const float* r = a + (size_t)row * n;
    float m = -1e30f;
    for (int i = tid; i < n; i += 256) m = fmaxf(m, r[i]);
    red[tid] = m; __syncthreads();
    for (int s = 128; s > 0; s >>= 1) { if (tid < s) red[tid] = fmaxf(red[tid], red[tid + s]); __syncthreads(); }
    m = red[0]; __syncthreads();
    float acc = 0.f;
    for (int i = tid; i < n; i += 256) acc += expf(r[i] - m);
    red[tid] = acc; __syncthreads();
    for (int s = 128; s > 0; s >>= 1) { if (tid < s) red[tid] += red[tid + s]; __syncthreads(); }
    const float inv = 1.0f / red[0];
    for (int i = tid; i < n; i += 256) o[(size_t)row * n + i] = expf(r[i] - m) * inv;
}

__global__ void gemm_M_k(const float* __restrict__ sa_w, const float* __restrict__ attnS,
                         float* __restrict__ M) {
    int idx = blockIdx.x * 256 + threadIdx.x;
    if (idx >= H1 * C0) return;
    int o = idx / C0, c = idx - o * C0;
    float s = 0.f;
    for (int i = 0; i < C0; ++i) s = fmaf(sa_w[(size_t)o * C0 + i], attnS[(size_t)i * C0 + c], s);
    M[idx] = s;
}

// fragment-order weights: chunk ((cc*K+k)*OB32 + ob)*2 + kk; lane holds o=ob*32+(l&31),
// c = cc*32 + kk*16 + (l>>5)*8 + j
__global__ void wfrag_k(const float* __restrict__ w, short* __restrict__ out,
                        int CIN, int O, int K, int NC) {
    int idx = blockIdx.x * 256 + threadIdx.x;
    int OB32 = O / 32;
    int total = NC * K * OB32 * 2 * 512;
    if (idx >= total) return;
    int j = idx & 7, lane = (idx >> 3) & 63, kk = (idx >> 9) & 1, r = idx >> 10;
    int ob = r % OB32, r2 = r / OB32;
    int k = r2 % K, cc = r2 / K;
    int o = ob * 32 + (lane & 31);
    int c = cc * 32 + kk * 16 + (lane >> 5) * 8 + j;
    float v = (c < CIN) ? w[((size_t)o * CIN + c) * K + k] : 0.f;
    out[idx] = f2bf(v);
}

// stage-A fused weights, fragment order, NC=10: sum_h subj_w[s][o][h]*M[h][c]
__global__ void msubA_k(const float* __restrict__ subj_w, const float* __restrict__ M,
                        short* __restrict__ out) {
    int idx = blockIdx.x * 256 + threadIdx.x;
    const int per_s = 10 * 1 * 4 * 2 * 512;
    if (idx >= 4 * per_s) return;
    int s = idx / per_s, rem = idx % per_s;
    int j = rem & 7, lane = (rem >> 3) & 63, kk = (rem >> 9) & 1, r = rem >> 10;
    int ob = r % 4, cc = r / 4;
    int o = ob * 32 + (lane & 31);
    int c = cc * 32 + kk * 16 + (lane >> 5) * 8 + j;
    float a = 0.f;
    if (c < C0) {
        const float* wr = subj_w + ((size_t)s * 128 + o) * 128;
        for (int h = 0; h < 128; ++h) a = fmaf(wr[h], M[(size_t)h * C0 + c], a);
    }
    out[idx] = f2bf(a);
}

__global__ void biasS_k(const float* __restrict__ subj_w, const float* __restrict__ sa_b,
                        const float* __restrict__ subj_b, float* __restrict__ biasS) {
    int idx = blockIdx.x * 256 + threadIdx.x;
    if (idx >= 4 * H1) return;
    int s = idx >> 7, o = idx & 127;
    const float* wr = subj_w + ((size_t)s * H1 + o) * H1;
    float a = subj_b[idx];
    for (int h = 0; h < H1; ++h) a = fmaf(wr[h], sa_b[h], a);
    biasS[idx] = a;
}

// X [b][c][t] fp32 -> xT [b][row=t+1][288] bf16
__global__ void xpose_k(const float* __restrict__ X, short* __restrict__ xT) {
    __shared__ float tile[32][33];
    int b = blockIdx.z;
    int t0 = blockIdx.x * 32, c0 = blockIdx.y * 32;
    int tx = threadIdx.x, ty = threadIdx.y;
    #pragma unroll
    for (int i = 0; i < 4; ++i) {
        int c = c0 + ty + i * 8, t = t0 + tx;
        float v = 0.f;
        if (c < C0 && t < Tt) v = X[((size_t)b * C0 + c) * Tt + t];
        tile[ty + i * 8][tx] = v;
    }
    __syncthreads();
    #pragma unroll
    for (int i = 0; i < 4; ++i) {
        int t = t0 + ty + i * 8, c = c0 + tx;
        if (t < Tt) xT[((size_t)b * TR + t + 1) * CP0 + c] = f2bf(tile[tx][ty + i * 8]);
    }
}

// ---------------- small-block conv kernel: 96t x O_BLK, 26KB LDS ring ----------------
// Many independent blocks per CU (TLP hides stalls). Weights direct from L2 in
// fragment order (once per block). X staged as 64-ch (cc-pair) double-buffered ring
// via global_load_lds with XOR-8 unit swizzle; counted vmcnt keeps prefetch in flight.
// Non-temporal res-load/out-store protect weight L2 residency (r5 failure mode).

template<int K, int NCC, int O_BLK, bool GELU, bool HASRES, bool POOL>
__global__ __launch_bounds__((O_BLK / 64) * 64, 3)
void convSB(const short* __restrict__ xin, int XC,
            const short* __restrict__ wf,
            const float* __restrict__ bias,
            const float* __restrict__ gamma, const float* __restrict__ beta,
            const short* __restrict__ res, short* __restrict__ outp,
            float* __restrict__ pooled,
            const int* __restrict__ sidx, int wsub, int bsub)
{
    constexpr int NW   = O_BLK / 64;          // waves per block (2 or 4)
    constexpr int NT   = NW * 64;
    constexpr int OB32 = O_BLK / 32;
    constexpr int NP   = NCC / 2;             // cc-pair phases
    constexpr int ROFF = 1 - (K - 1) / 2;
    constexpr int O2   = O_BLK * 2;
    constexpr int RCH  = O_BLK / 8;
    constexpr int BUFB = 13312;               // 104 rows * 128 B

    __shared__ __align__(16) char smem[2 * BUFB];

    const int t0   = blockIdx.x * 96;
    const int b    = blockIdx.y;
    const int tid  = threadIdx.x;
    const int lane = tid & 63, w = tid >> 6;
    const int l31  = lane & 31, hi = lane >> 5;

    int subj = sidx ? sidx[b] : 0;
    const short* wb = wf + (size_t)subj * wsub;
    const float* bb = bias + (size_t)subj * bsub;

    f32x16 acc[2][3];
    #pragma unroll
    for (int i = 0; i < 2; ++i)
        #pragma unroll
        for (int j = 0; j < 3; ++j)
            #pragma unroll
            for (int e = 0; e < 16; ++e) acc[i][j][e] = 0.f;

    auto issue = [&](int pair, int bi) {
        #pragma unroll
        for (int i = 0; i < 13; ++i) {
            if ((i & (NW - 1)) == w) {
                int pos = i * 1024 + lane * 16;
                int r = pos >> 7;              // 0..103
                int u = (pos >> 4) & 7;
                int us = u ^ (r & 7);
                int rr = t0 + r; if (rr > 291) rr = 291;
                gl16(xin + ((size_t)b * TR + rr) * XC + (pair * 8 + us) * 8,
                     smem + bi * BUFB + i * 1024);
            }
        }
    };

    issue(0, 0);
    #pragma unroll
    for (int p = 0; p < NP; ++p) {
        __builtin_amdgcn_sched_barrier(0);
        if (p + 1 < NP) issue(p + 1, (p + 1) & 1);
        __builtin_amdgcn_sched_barrier(0);
        if (p + 1 < NP) {
            // FIFO: wait until only the just-issued stage remains outstanding
            if constexpr (NW == 2) { if (w == 0) waitv<7>(); else waitv<6>(); }
            else                   { if (w == 0) waitv<4>(); else waitv<3>(); }
        } else {
            waitv<0>();
        }
        hard_barrier();
        const char* Xb = smem + (p & 1) * BUFB;
        #pragma unroll
        for (int cj = 0; cj < 2; ++cj) {
            const int cc = 2 * p + cj;
            s16x8 a0[K][2], a1[K][2];
            #pragma unroll
            for (int k = 0; k < K; ++k)
                #pragma unroll
                for (int kk = 0; kk < 2; ++kk) {
                    size_t ci0 = (size_t)(((cc * K + k) * OB32 + w * 2 + 0) * 2 + kk) * 512;
                    size_t ci1 = (size_t)(((cc * K + k) * OB32 + w * 2 + 1) * 2 + kk) * 512;
                    a0[k][kk] = *(const s16x8*)(wb + ci0 + lane * 8);
                    a1[k][kk] = *(const s16x8*)(wb + ci1 + lane * 8);
                }
            __builtin_amdgcn_s_setprio(1);
            #pragma unroll
            for (int k = 0; k < K; ++k)
                #pragma unroll
                for (int kk = 0; kk < 2; ++kk)
                    #pragma unroll
                    for (int ts = 0; ts < 3; ++ts) {
                        int rl = ts * 32 + l31 + k + ROFF;
                        s16x8 bv = *(const s16x8*)(Xb + rl * 128 +
                            (((cj * 4 + kk * 2 + hi) ^ (rl & 7)) << 4));
                        acc[0][ts] = __builtin_amdgcn_mfma_f32_32x32x16_bf16(a0[k][kk], bv, acc[0][ts], 0, 0, 0);
                        acc[1][ts] = __builtin_amdgcn_mfma_f32_32x32x16_bf16(a1[k][kk], bv, acc[1][ts], 0, 0, 0);
                    }
            __builtin_amdgcn_s_setprio(0);
        }
        hard_barrier();
    }

    // ---- epilogue: 3 sections (one 32-t slice each) through LDS, coalesced stores ----
    float ps[8];
    if constexpr (POOL) {
        #pragma unroll
        for (int j = 0; j < 8; ++j) ps[j] = 0.f;
    }

    #pragma unroll
    for (int g = 0; g < 3; ++g) {
        hard_barrier();
        #pragma unroll
        for (int os = 0; os < 2; ++os) {
            #pragma unroll
            for (int rq = 0; rq < 4; ++rq)
                #pragma unroll
                for (int rp = 0; rp < 2; ++rp) {
                    const int oc = w * 64 + os * 32 + 8 * rq + rp * 2 + 4 * hi;
                    const float bv0 = bb[oc], bv1 = bb[oc + 1];
                    const float g0 = gamma ? gamma[oc] * BN_INV : 1.f;
                    const float g1 = gamma ? gamma[oc + 1] * BN_INV : 1.f;
                    const float e0 = beta ? beta[oc] : 0.f;
                    const float e1 = beta ? beta[oc + 1] : 0.f;
                    const int r0 = rq * 4 + rp * 2;
                    float v0 = (acc[os][g][r0] + bv0) * g0 + e0;
                    float v1 = (acc[os][g][r0 + 1] + bv1) * g1 + e1;
                    int byte = l31 * O2 + ((oc * 2) ^ ((l31 & 15) << 4));
                    __hip_bfloat162 pk;
                    pk.x = __float2bfloat16(v0);
                    pk.y = __float2bfloat16(v1);
                    *(__hip_bfloat162*)(smem + byte) = pk;
                }
        }
        hard_barrier();
        for (int q = tid; q < 32 * RCH; q += NT) {
            int rr = q / RCH, cp = q - rr * RCH;
            int tt = t0 + g * 32 + rr;
            if (tt >= Tt) continue;
            s16x8 hv = *(const s16x8*)(smem + rr * O2 + ((cp * 16) ^ ((rr & 15) << 4)));
            size_t orow = ((size_t)b * TR + tt + 1) * O_BLK + cp * 8;
            s16x8 rv;
            if (HASRES) rv = __builtin_nontemporal_load((const s16x8*)(res + orow));
            if constexpr (POOL) {
                #pragma unroll
                for (int j = 0; j < 8; ++j) {
                    float v = bf2f(hv[j]);
                    if (HASRES) v += bf2f(rv[j]);
                    if (GELU) v = gelu_f(v);
                    ps[j] += v;
                }
            } else {
                s16x8 ov;
                #pragma unroll
                for (int j = 0; j < 8; ++j) {
                    float v = bf2f(hv[j]);
                    if (HASRES) v += bf2f(rv[j]);
                    if (GELU) v = gelu_f(v);
                    ov[j] = f2bf(v);
                }
                __builtin_nontemporal_store(ov, (s16x8*)(outp + orow));
            }
        }
    }

    if constexpr (POOL) {
        // thread's cp = tid % RCH is constant (NT % RCH == 0): LDS reduce + one atomic
        constexpr int NRED = NT / RCH;
        float* part = (float*)smem;
        hard_barrier();
        #pragma unroll
        for (int j = 0; j < 8; ++j) part[tid * 8 + j] = ps[j];
        hard_barrier();
        if (tid < O_BLK) {
            int cp = tid >> 3, j = tid & 7;
            float s = 0.f;
            #pragma unroll
            for (int r = 0; r < NRED; ++r) s += part[(cp + RCH * r) * 8 + j];
            atomicAdd(pooled + (size_t)b * H2 + tid, s * (1.0f / 281.0f));
        }
    }
}

// ---------------- head kernels ----------------

__global__ void head1_k(const float* __restrict__ pooled, const float* __restrict__ emb,
                        const int* __restrict__ sidx, const float* __restrict__ w1,
                        const float* __restrict__ b1, float* __restrict__ hout) {
    int idx = blockIdx.x * 256 + threadIdx.x;
    if (idx >= Bz * H1) return;
    int b = idx >> 7, j = idx & 127;
    const float* wr = w1 + (size_t)j * (H2 + ED);
    const float* pr = pooled + (size_t)b * H2;
    float a = b1[j];
    for (int i = 0; i < H2; ++i) a = fmaf(pr[i], wr[i], a);
    const float* er = emb + (size_t)sidx[b] * ED;
    #pragma unroll
    for (int e = 0; e < ED; ++e) a = fmaf(er[e], wr[H2 + e], a);
    hout[idx] = fmaxf(a, 0.f);
}

__global__ __launch_bounds__(256)
void head2_k(const float* __restrict__ h, const float* __restrict__ w2,
             const float* __restrict__ b2, float* __restrict__ out) {
    const int n0 = blockIdx.x * 64;
    const int b0 = blockIdx.y * 16;
    __shared__ float hs[16][128];
    __shared__ float w2s[64][129];
    const int tid = threadIdx.x;
    for (int idx = tid; idx < 16 * 128; idx += 256) {
        int bl = idx >> 7, j = idx & 127;
        hs[bl][j] = h[(size_t)(b0 + bl) * H1 + j];
    }
    for (int idx = tid; idx < 64 * 128; idx += 256) {
        int nl = idx >> 7, j = idx & 127;
        int n = n0 + nl;
        w2s[nl][j] = (n < NCLS) ? w2[(size_t)n * H1 + j] : 0.f;
    }
    __syncthreads();
    const int nl = tid & 63, bg = tid >> 6;
    float acc[4] = {0.f, 0.f, 0.f, 0.f};
    for (int j = 0; j < 128; ++j) {
        const float wv = w2s[nl][j];
        #pragma unroll
        for (int bb = 0; bb < 4; ++bb) acc[bb] = fmaf(wv, hs[bg * 4 + bb][j], acc[bb]);
    }
    const int n = n0 + nl;
    if (n < NCLS) {
        const float bv = b2[n];
        #pragma unroll
        for (int bb = 0; bb < 4; ++bb)
            out[(size_t)(b0 + bg * 4 + bb) * NCLS + n] = acc[bb] + bv;
    }
}

// ---------------- host launch ----------------

extern "C" void kernel_launch(void* const* d_in, const int* in_sizes, int n_in,
                              void* d_out, int out_size, void* d_ws, size_t ws_size,
                              hipStream_t stream) {
    const float* X      = (const float*)d_in[0];
    const int*   sidx   = (const int*)  d_in[1];
    const float* attn   = (const float*)d_in[2];
    const float* sa_w   = (const float*)d_in[3];
    const float* sa_b   = (const float*)d_in[4];
    const float* subj_w = (const float*)d_in[5];
    const float* subj_b = (const float*)d_in[6];
    const float* b1c1w = (const float*)d_in[7];  const float* b1c1b = (const float*)d_in[8];
    const float* b1c2w = (const float*)d_in[9];  const float* b1c2b = (const float*)d_in[10];
    const float* b1g1  = (const float*)d_in[11]; const float* b1be1 = (const float*)d_in[12];
    const float* b1g2  = (const float*)d_in[13]; const float* b1be2 = (const float*)d_in[14];
    const float* b2c1w = (const float*)d_in[15]; const float* b2c1b = (const float*)d_in[16];
    const float* b2c2w = (const float*)d_in[17]; const float* b2c2b = (const float*)d_in[18];
    const float* b2g1  = (const float*)d_in[19]; const float* b2be1 = (const float*)d_in[20];
    const float* b2g2  = (const float*)d_in[21]; const float* b2be2 = (const float*)d_in[22];
    const float* b2skw = (const float*)d_in[23]; const float* b2skb = (const float*)d_in[24];
    const float* b3c1w = (const float*)d_in[25]; const float* b3c1b = (const float*)d_in[26];
    const float* b3c2w = (const float*)d_in[27]; const float* b3c2b = (const float*)d_in[28];
    const float* b3g1  = (const float*)d_in[29]; const float* b3be1 = (const float*)d_in[30];
    const float* b3g2  = (const float*)d_in[31]; const float* b3be2 = (const float*)d_in[32];
    const float* emb   = (const float*)d_in[33];
    const float* hw1   = (const float*)d_in[34]; const float* hb1 = (const float*)d_in[35];
    const float* hw2   = (const float*)d_in[36]; const float* hb2 = (const float*)d_in[37];
    float* out = (float*)d_out;
    (void)in_sizes; (void)n_in; (void)out_size; (void)ws_size;

    char* wsp = (char*)d_ws;
    size_t off = 0;
    auto allocF = [&](size_t n) {
        float* p = (float*)(wsp + off);
        off += ((n * sizeof(float)) + 255) & ~(size_t)255;
        return p;
    };
    auto allocS = [&](size_t n) {
        short* p = (short*)(wsp + off);
        off += ((n * sizeof(short)) + 255) & ~(size_t)255;
        return p;
    };
    float* attnS   = allocF((size_t)C0 * C0);
    float* Mmat    = allocF((size_t)H1 * C0);
    float* biasS   = allocF((size_t)4 * H1);
    float* pooled  = allocF((size_t)Bz * H2);
    float* hbuf    = allocF((size_t)Bz * H1);
    short* wStageA = allocS((size_t)4 * 10 * 4 * 2 * 512);    // per-subj 40960 (NC=10)
    short* wp_b1c1 = allocS((size_t)4 * 3 * 4 * 2 * 512);
    short* wp_b1c2 = allocS((size_t)4 * 3 * 4 * 2 * 512);
    short* wp_skip = allocS((size_t)4 * 1 * 8 * 2 * 512);
    short* wp_b2c1 = allocS((size_t)4 * 3 * 8 * 2 * 512);
    short* wp_b2c2 = allocS((size_t)8 * 3 * 8 * 2 * 512);
    short* wp_b3c1 = allocS((size_t)8 * 3 * 8 * 2 * 512);
    short* wp_b3c2 = allocS((size_t)8 * 3 * 8 * 2 * 512);
    short* xT   = allocS((size_t)Bz * TR * CP0 + 64);   // +64 pad: unit 36..39 over-read guard
    short* bufP = allocS((size_t)Bz * TR * H1);
    short* bufQ = allocS((size_t)Bz * TR * H1);
    short* bufR = allocS((size_t)Bz * TR * H2);
    short* bufS = allocS((size_t)Bz * TR * H2);

    // ---- zero margin rows + pooled ----
    zrows_k<<<Bz, 256, 0, stream>>>(xT, CP0);
    zrows_k<<<Bz, 256, 0, stream>>>(bufP, H1);
    zrows_k<<<Bz, 256, 0, stream>>>(bufQ, H1);
    zrows_k<<<Bz, 256, 0, stream>>>(bufR, H2);
    zrows_k<<<Bz, 256, 0, stream>>>(bufS, H2);
    zerof_k<<<(Bz * H2 + 255) / 256, 256, 0, stream>>>(pooled, Bz * H2);

    // ---- prep ----
    softmax_rows_k<<<C0, 256, 0, stream>>>(attn, attnS, C0);
    gemm_M_k<<<(H1 * C0 + 255) / 256, 256, 0, stream>>>(sa_w, attnS, Mmat);
    msubA_k<<<(4 * 40960 + 255) / 256, 256, 0, stream>>>(subj_w, Mmat, wStageA);
    biasS_k<<<2, 256, 0, stream>>>(subj_w, sa_b, subj_b, biasS);
    wfrag_k<<<(4*3*4*2*512 + 255) / 256, 256, 0, stream>>>(b1c1w, wp_b1c1, 128, 128, 3, 4);
    wfrag_k<<<(4*3*4*2*512 + 255) / 256, 256, 0, stream>>>(b1c2w, wp_b1c2, 128, 128, 3, 4);
    wfrag_k<<<(4*1*8*2*512 + 255) / 256, 256, 0, stream>>>(b2skw, wp_skip, 128, 256, 1, 4);
    wfrag_k<<<(4*3*8*2*512 + 255) / 256, 256, 0, stream>>>(b2c1w, wp_b2c1, 128, 256, 3, 4);
    wfrag_k<<<(8*3*8*2*512 + 255) / 256, 256, 0, stream>>>(b2c2w, wp_b2c2, 256, 256, 3, 8);
    wfrag_k<<<(8*3*8*2*512 + 255) / 256, 256, 0, stream>>>(b3c1w, wp_b3c1, 256, 256, 3, 8);
    wfrag_k<<<(8*3*8*2*512 + 255) / 256, 256, 0, stream>>>(b3c2w, wp_b3c2, 256, 256, 3, 8);
    xpose_k<<<dim3(9, 9, Bz), dim3(32, 8), 0, stream>>>(X, xT);

    dim3 cg(3, Bz);

    // ---- conv stack: <K, NCC, O_BLK, GELU, HASRES, POOL> ----
    // stageA: xT(288ch, NCC=10) -> P(128), per-subject weights
    convSB<1, 10, 128, false, false, false><<<cg, 128, 0, stream>>>(
        xT, CP0, wStageA, biasS, nullptr, nullptr, nullptr, bufP, nullptr, sidx, 40960, 128);
    // block1: P -> Q (gelu+bn); Q (+res P) -> P in-place
    convSB<3, 4, 128, true, false, false><<<cg, 128, 0, stream>>>(
        bufP, H1, wp_b1c1, b1c1b, b1g1, b1be1, nullptr, bufQ, nullptr, nullptr, 0, 0);
    convSB<3, 4, 128, true, true, false><<<cg, 128, 0, stream>>>(
        bufQ, H1, wp_b1c2, b1c2b, b1g2, b1be2, bufP, bufP, nullptr, nullptr, 0, 0);
    // block2: skip P->S; c1 P->R; c2 R(+res S)->S in-place
    convSB<1, 4, 256, false, false, false><<<cg, 256, 0, stream>>>(
        bufP, H1, wp_skip, b2skb, nullptr, nullptr, nullptr, bufS, nullptr, nullptr, 0, 0);
    convSB<3, 4, 256, true, false, false><<<cg, 256, 0, stream>>>(
        bufP, H1, wp_b2c1, b2c1b, b2g1, b2be1, nullptr, bufR, nullptr, nullptr, 0, 0);
    convSB<3, 8, 256, true, true, false><<<cg, 256, 0, stream>>>(
        bufR, H2, wp_b2c2, b2c2b, b2g2, b2be2, bufS, bufS, nullptr, nullptr, 0, 0);
    // block3: c1 S->R; c2 R(+res S) -> fused global-avg-pool (atomic per channel)
    convSB<3, 8, 256, true, false, false><<<cg, 256, 0, stream>>>(
        bufS, H2, wp_b3c1, b3c1b, b3g1, b3be1, nullptr, bufR, nullptr, nullptr, 0, 0);
    convSB<3, 8, 256, true, true, true><<<cg, 256, 0, stream>>>(
        bufR, H2, wp_b3c2, b3c2b, b3g2, b3be2, bufS, nullptr, pooled, nullptr, 0, 0);

    // ---- head ----
    head1_k<<<(Bz * H1 + 255) / 256, 256, 0, stream>>>(pooled, emb, sidx, hw1, hb1, hbuf);
    head2_k<<<dim3((NCLS + 63) / 64, Bz / 16), 256, 0, stream>>>(hbuf, hw2, hb2, out);
}

// Round 10
// 1609.069 us; speedup vs baseline: 7.8891x; 1.0400x over previous
//
#include <hip/hip_runtime.h>
#include <hip/hip_bf16.h>
#include <math.h>

constexpr int Bz = 1024;
constexpr int C0 = 271;   // input channels
constexpr int CP0 = 288;  // padded to 9*32
constexpr int Tt = 281;   // time
constexpr int TR = 292;   // padded rows per batch: row = t+1; rows 0,282..291 zero
constexpr int H1 = 128;
constexpr int H2 = 256;
constexpr int NCLS = 1854;
constexpr int ED = 16;
constexpr float BN_INV = 0.9999950000374996f;  // 1/sqrt(1+1e-5)

typedef __attribute__((ext_vector_type(8))) short s16x8;
typedef __attribute__((ext_vector_type(16))) float f32x16;

// fast erf (Abramowitz-Stegun 7.1.26, |eps| < 1.5e-7)
__device__ __forceinline__ float erf_fast(float x) {
    float ax = fabsf(x);
    float t = __builtin_amdgcn_rcpf(fmaf(0.3275911f, ax, 1.0f));
    float p = fmaf(1.061405429f, t, -1.453152027f);
    p = fmaf(p, t, 1.421413741f);
    p = fmaf(p, t, -0.284496736f);
    p = fmaf(p, t, 0.254829592f);
    float e = __expf(-ax * ax);
    float r = fmaf(-p * t, e, 1.0f);
    return copysignf(r, x);
}
__device__ __forceinline__ float gelu_f(float v) {
    return 0.5f * v * (1.0f + erf_fast(v * 0.7071067811865475f));
}
__device__ __forceinline__ float bf2f(short s) {
    return __builtin_bit_cast(float, ((unsigned int)(unsigned short)s) << 16);
}
__device__ __forceinline__ short f2bf(float f) {
    return __builtin_bit_cast(short, __float2bfloat16(f));
}

typedef unsigned int u32;
typedef const __attribute__((address_space(1))) u32 gu32;
typedef __attribute__((address_space(3))) u32 lu32;

__device__ __forceinline__ void gl16(const void* g, void* l) {
    __builtin_amdgcn_global_load_lds((gu32*)(uintptr_t)g, (lu32*)(uintptr_t)l, 16, 0, 0);
}
template<int N> __device__ __forceinline__ void waitv() {
    asm volatile("s_waitcnt vmcnt(%0)" :: "i"(N) : "memory");
}
__device__ __forceinline__ void hard_barrier() {
    __builtin_amdgcn_sched_barrier(0);
    __builtin_amdgcn_s_barrier();
    __builtin_amdgcn_sched_barrier(0);
}

// ---------------- prep kernels ----------------

__global__ void zrows_k(short* base, int C) {
    const int b = blockIdx.x;
    const int n = 11 * (C / 8);
    for (int i = threadIdx.x; i < n; i += 256) {
        int ri = i / (C / 8), c8 = i - ri * (C / 8);
        int row = (ri == 0) ? 0 : 281 + ri;   // 0, 282..291
        *(int4*)(base + ((size_t)b * TR + row) * C + c8 * 8) = make_int4(0, 0, 0, 0);
    }
}

__global__ void softmax_rows_k(const float* __restrict__ a, float* __restrict__ o, int n) {
    __shared__ float red[256];
    const int row = blockIdx.x, tid = threadIdx.x;
    const float* r = a + (size_t)row * n;
    float m = -1e30f;
    for (int i = tid; i < n; i += 256) m = fmaxf(m, r[i]);
    red[tid] = m; __syncthreads();
    for (int s = 128; s > 0; s >>= 1) { if (tid < s) red[tid] = fmaxf(red[tid], red[tid + s]); __syncthreads(); }
    m = red[0]; __syncthreads();
    float acc = 0.f;
    for (int i = tid; i < n; i += 256) acc += expf(r[i] - m);
    red[tid] = acc; __syncthreads();
    for (int s = 128; s > 0; s >>= 1) { if (tid < s) red[tid] += red[tid + s]; __syncthreads(); }
    const float inv = 1.0f / red[0];
    for (int i = tid; i < n; i += 256) o[(size_t)row * n + i] = expf(r[i] - m) * inv;
}

__global__ void gemm_M_k(const float* __restrict__ sa_w, const float* __restrict__ attnS,
                         float* __restrict__ M) {
    int idx = blockIdx.x * 256 + threadIdx.x;
    if (idx >= H1 * C0) return;
    int o = idx / C0, c = idx - o * C0;
    float s = 0.f;
    for (int i = 0; i < C0; ++i) s = fmaf(sa_w[(size_t)o * C0 + i], attnS[(size_t)i * C0 + c], s);
    M[idx] = s;
}

// fragment-order weights: chunk ((cc*K+k)*OB32 + ob)*2 + kk; lane holds o=ob*32+(l&31),
// c = cc*32 + kk*16 + (l>>5)*8 + j
__global__ void wfrag_k(const float* __restrict__ w, short* __restrict__ out,
                        int CIN, int O, int K, int NC) {
    int idx = blockIdx.x * 256 + threadIdx.x;
    int OB32 = O / 32;
    int total = NC * K * OB32 * 2 * 512;
    if (idx >= total) return;
    int j = idx & 7, lane = (idx >> 3) & 63, kk = (idx >> 9) & 1, r = idx >> 10;
    int ob = r % OB32, r2 = r / OB32;
    int k = r2 % K, cc = r2 / K;
    int o = ob * 32 + (lane & 31);
    int c = cc * 32 + kk * 16 + (lane >> 5) * 8 + j;
    float v = (c < CIN) ? w[((size_t)o * CIN + c) * K + k] : 0.f;
    out[idx] = f2bf(v);
}

// stage-A fused weights, fragment order, NC=10: sum_h subj_w[s][o][h]*M[h][c]
__global__ void msubA_k(const float* __restrict__ subj_w, const float* __restrict__ M,
                        short* __restrict__ out) {
    int idx = blockIdx.x * 256 + threadIdx.x;
    const int per_s = 10 * 1 * 4 * 2 * 512;
    if (idx >= 4 * per_s) return;
    int s = idx / per_s, rem = idx % per_s;
    int j = rem & 7, lane = (rem >> 3) & 63, kk = (rem >> 9) & 1, r = rem >> 10;
    int ob = r % 4, cc = r / 4;
    int o = ob * 32 + (lane & 31);
    int c = cc * 32 + kk * 16 + (lane >> 5) * 8 + j;
    float a = 0.f;
    if (c < C0) {
        const float* wr = subj_w + ((size_t)s * 128 + o) * 128;
        for (int h = 0; h < 128; ++h) a = fmaf(wr[h], M[(size_t)h * C0 + c], a);
    }
    out[idx] = f2bf(a);
}

__global__ void biasS_k(const float* __restrict__ subj_w, const float* __restrict__ sa_b,
                        const float* __restrict__ subj_b, float* __restrict__ biasS) {
    int idx = blockIdx.x * 256 + threadIdx.x;
    if (idx >= 4 * H1) return;
    int s = idx >> 7, o = idx & 127;
    const float* wr = subj_w + ((size_t)s * H1 + o) * H1;
    float a = subj_b[idx];
    for (int h = 0; h < H1; ++h) a = fmaf(wr[h], sa_b[h], a);
    biasS[idx] = a;
}

// X [b][c][t] fp32 -> xT [b][row=t+1][288] bf16
__global__ void xpose_k(const float* __restrict__ X, short* __restrict__ xT) {
    __shared__ float tile[32][33];
    int b = blockIdx.z;
    int t0 = blockIdx.x * 32, c0 = blockIdx.y * 32;
    int tx = threadIdx.x, ty = threadIdx.y;
    #pragma unroll
    for (int i = 0; i < 4; ++i) {
        int c = c0 + ty + i * 8, t = t0 + tx;
        float v = 0.f;
        if (c < C0 && t < Tt) v = X[((size_t)b * C0 + c) * Tt + t];
        tile[ty + i * 8][tx] = v;
    }
    __syncthreads();
    #pragma unroll
    for (int i = 0; i < 4; ++i) {
        int t = t0 + ty + i * 8, c = c0 + tx;
        if (t < Tt) xT[((size_t)b * TR + t + 1) * CP0 + c] = f2bf(tile[tx][ty + i * 8]);
    }
}

// ---------------- overlap conv kernel: split-stage + cc-rotation ----------------
// Full-T blocks, NB batches x O_BLK. X in LDS as cc-pair slices (304 rows x 128 B,
// XOR-8 unit swizzle, stage-src pre-swizzled = read swizzle). BOTH stage halves
// issued up-front; counted vmcnt waits only for half 1 -> half 2 lands under
// compute. Waves rotate cc order within a phase (LDS-resident -> legal) so A-L2,
// LDS and MFMA pipes are hit at different times per wave (anti-convoy).

constexpr int SLICEB = 38912;   // 304 rows * 128 B = one cc-pair slice

template<int K, int OB32>
__device__ __forceinline__ void comp_cc(
    f32x16 (&acc)[2][3], const short* __restrict__ wb, const char* Xslot, int cc,
    int tg, int lane, int l31, int hi, int wvo)
{
    constexpr int ROFF = 1 - (K - 1) / 2;
    s16x8 a[2][K][2];
    #pragma unroll
    for (int os = 0; os < 2; ++os)
        #pragma unroll
        for (int k = 0; k < K; ++k)
            #pragma unroll
            for (int kk = 0; kk < 2; ++kk) {
                int ci = ((cc * K + k) * OB32 + wvo * 2 + os) * 2 + kk;
                a[os][k][kk] = *(const s16x8*)(wb + (size_t)ci * 512 + lane * 8);
            }
    __builtin_amdgcn_s_setprio(1);
    #pragma unroll
    for (int k = 0; k < K; ++k)
        #pragma unroll
        for (int kk = 0; kk < 2; ++kk)
            #pragma unroll
            for (int ts = 0; ts < 3; ++ts) {
                int rl = tg + ts * 32 + l31 + k + ROFF;
                s16x8 bv = *(const s16x8*)(Xslot + rl * 128 +
                    ((((cc & 1) * 4 + kk * 2 + hi) ^ (rl & 7)) << 4));
                acc[0][ts] = __builtin_amdgcn_mfma_f32_32x32x16_bf16(a[0][k][kk], bv, acc[0][ts], 0, 0, 0);
                acc[1][ts] = __builtin_amdgcn_mfma_f32_32x32x16_bf16(a[1][k][kk], bv, acc[1][ts], 0, 0, 0);
            }
    __builtin_amdgcn_s_setprio(0);
}

template<int K, int NCC, int O_BLK, int NOW, int NB, bool GELU, bool HASRES, bool POOL>
__global__ __launch_bounds__(NOW * NB * 192)
void convOV(const short* __restrict__ xin, int XC,
            const short* __restrict__ wf,
            const float* __restrict__ bias,
            const float* __restrict__ gamma, const float* __restrict__ beta,
            const short* __restrict__ res, short* __restrict__ outp,
            float* __restrict__ pooled,
            const int* __restrict__ sidx, int wsub, int bsub)
{
    constexpr int NW   = NOW * NB * 3;
    constexpr int NT   = NW * 64;
    constexpr int OB32 = O_BLK / 32;
    constexpr int NSLT = (NCC == 10) ? 4 : NCC / 2;   // resident slots per batch
    constexpr int O2   = O_BLK * 2;
    constexpr int RCH  = O_BLK / 8;

    __shared__ __align__(16) char smem[NB * NSLT * SLICEB];

    const int b0   = blockIdx.x * NB;
    const int tid  = threadIdx.x;
    const int lane = tid & 63, wv = tid >> 6;
    const int l31  = lane & 31, hi = lane >> 5;
    const int bqw  = wv / (NOW * 3);
    const int w2   = wv % (NOW * 3);
    const int wvt  = w2 / NOW;          // t-group 0..2
    const int wvo  = w2 % NOW;          // o-group
    const int tg   = wvt * 96;

    int subj = sidx ? sidx[b0] : 0;
    const short* wb = wf + (size_t)subj * wsub;
    const float* bb = bias + (size_t)subj * bsub;

    f32x16 acc[2][3];
    #pragma unroll
    for (int i = 0; i < 2; ++i)
        #pragma unroll
        for (int j = 0; j < 3; ++j)
            #pragma unroll
            for (int e = 0; e < 16; ++e) acc[i][j][e] = 0.f;

    // stage `nsl` slices (global ccpair gp0..) into slots slot0.. for all NB batches
    auto stage = [&](int gp0, int slot0, int nsl) {
        const int C = NB * nsl * 38;
        for (int i = wv; i < C; i += NW) {
            int bl = i / (nsl * 38);
            int rem = i - bl * (nsl * 38);
            int s = rem / 38, jj = rem - s * 38;
            int pos = jj * 1024 + lane * 16;
            int r = pos >> 7;              // 0..303
            int up = (pos >> 4) & 7;
            int us = up ^ (r & 7);
            int rr = r > 291 ? 291 : r;
            gl16(xin + ((size_t)(b0 + bl) * TR + rr) * XC + ((gp0 + s) * 8 + us) * 8,
                 smem + ((size_t)bl * NSLT + slot0 + s) * SLICEB + jj * 1024);
        }
    };

    const char* Xb = smem + (size_t)bqw * NSLT * SLICEB;

    if constexpr (NCC != 10) {
        constexpr int NSL1 = NSLT / 2;          // 1 or 2
        constexpr int NSL2 = NSLT - NSL1;
        constexpr int C2 = NB * NSL2 * 38;
        constexpr int Q2 = C2 / NW, R2 = C2 % NW;
        constexpr int P1 = 2 * NSL1, P2 = 2 * NSL2;   // cc per phase (pow2)
        stage(0, 0, NSL1);
        stage(NSL1, NSL1, NSL2);
        if (wv < R2) waitv<Q2 + 1>(); else waitv<Q2>();
        hard_barrier();
        const int rot1 = wv & (P1 - 1), rot2 = wv & (P2 - 1);
        #pragma unroll
        for (int c = 0; c < P1; ++c) {
            int cc = (c + rot1) & (P1 - 1);
            comp_cc<K, OB32>(acc, wb, Xb + (cc >> 1) * SLICEB, cc, tg, lane, l31, hi, wvo);
        }
        waitv<0>();
        hard_barrier();
        #pragma unroll
        for (int c = 0; c < P2; ++c) {
            int cc = P1 + ((c + rot2) & (P2 - 1));
            comp_cc<K, OB32>(acc, wb, Xb + (cc >> 1) * SLICEB, cc, tg, lane, l31, hi, wvo);
        }
    } else {
        // stageA: 5 slices, 4 slots. s0-s3 up-front; wait s0-s2; compute cc0-5;
        // barrier; s4->slot0 (under cc6-7 compute); compute cc8-9.
        stage(0, 0, 4);
        if (wv < 2) waitv<7>(); else waitv<6>();    // own s3 chunks remain
        hard_barrier();
        const int rot6 = wv % 6;
        #pragma unroll
        for (int c = 0; c < 6; ++c) {
            int cc = (c + rot6) % 6;
            comp_cc<K, OB32>(acc, wb, Xb + (cc >> 1) * SLICEB, cc, tg, lane, l31, hi, wvo);
        }
        waitv<0>();       // ensure s3 fully landed (and drain)
        hard_barrier();   // all waves done reading slot 0
        stage(4, 0, 1);   // slice 4 -> slot 0
        #pragma unroll
        for (int c = 0; c < 2; ++c) {
            int cc = 6 + ((c + wv) & 1);
            comp_cc<K, OB32>(acc, wb, Xb + 3 * SLICEB, cc, tg, lane, l31, hi, wvo);
        }
        waitv<0>();
        hard_barrier();
        #pragma unroll
        for (int c = 0; c < 2; ++c) {
            int cc = 8 + ((c + wv) & 1);
            comp_cc<K, OB32>(acc, wb, Xb + 0 * SLICEB, cc, tg, lane, l31, hi, wvo);
        }
    }

    // ---------------- epilogue: 3 t-sections through LDS ----------------
    float ps[8];
    if constexpr (POOL) {
        #pragma unroll
        for (int j = 0; j < 8; ++j) ps[j] = 0.f;
    }
    for (int g = 0; g < 3; ++g) {
        hard_barrier();
        if (wvt == g) {
            #pragma unroll
            for (int os = 0; os < 2; ++os) {
                #pragma unroll
                for (int rq = 0; rq < 4; ++rq) {
                    #pragma unroll
                    for (int rp = 0; rp < 2; ++rp) {
                        const int oc = wvo * 64 + os * 32 + 8 * rq + rp * 2 + 4 * hi;
                        const float bv0 = bb[oc], bv1 = bb[oc + 1];
                        const float g0 = gamma ? gamma[oc] * BN_INV : 1.f;
                        const float g1 = gamma ? gamma[oc + 1] * BN_INV : 1.f;
                        const float e0 = beta ? beta[oc] : 0.f;
                        const float e1 = beta ? beta[oc + 1] : 0.f;
                        const int r0 = rq * 4 + rp * 2;
                        #pragma unroll
                        for (int ts = 0; ts < 3; ++ts) {
                            float v0 = (acc[os][ts][r0] + bv0) * g0 + e0;
                            float v1 = (acc[os][ts][r0 + 1] + bv1) * g1 + e1;
                            int tl = ts * 32 + l31;
                            int byte = (bqw * 96 + tl) * O2 + ((oc * 2) ^ ((tl & 15) << 4));
                            __hip_bfloat162 pk;
                            pk.x = __float2bfloat16(v0);
                            pk.y = __float2bfloat16(v1);
                            *(__hip_bfloat162*)(smem + byte) = pk;
                        }
                    }
                }
            }
        }
        hard_barrier();
        for (int qq = tid; qq < NB * 96 * RCH; qq += NT) {
            int bql = qq / (96 * RCH), rem = qq - bql * (96 * RCH);
            int r = rem / RCH, cp = rem - r * RCH;
            int t = g * 96 + r;
            if (t >= Tt) continue;
            s16x8 hv = *(const s16x8*)(smem + (bql * 96 + r) * O2 + ((cp * 16) ^ ((r & 15) << 4)));
            size_t orow = ((size_t)(b0 + bql) * TR + t + 1) * O_BLK + cp * 8;
            s16x8 rv;
            if (HASRES) rv = *(const s16x8*)(res + orow);
            if constexpr (POOL) {
                #pragma unroll
                for (int j = 0; j < 8; ++j) {
                    float v = bf2f(hv[j]);
                    if (HASRES) v += bf2f(rv[j]);
                    if (GELU) v = gelu_f(v);
                    ps[j] += v;
                }
            } else {
                s16x8 ov;
                #pragma unroll
                for (int j = 0; j < 8; ++j) {
                    float v = bf2f(hv[j]);
                    if (HASRES) v += bf2f(rv[j]);
                    if (GELU) v = gelu_f(v);
                    ov[j] = f2bf(v);
                }
                *(s16x8*)(outp + orow) = ov;
            }
        }
    }

    if constexpr (POOL) {
        // thread's cp = tid % RCH is constant (NT % RCH == 0): LDS reduce, direct store
        constexpr int NRED = NT / RCH;
        float* part = (float*)smem;
        hard_barrier();
        #pragma unroll
        for (int j = 0; j < 8; ++j) part[tid * 8 + j] = ps[j];
        hard_barrier();
        if (tid < O_BLK) {
            int cp = tid >> 3, j = tid & 7;
            float s = 0.f;
            for (int r = 0; r < NRED; ++r) s += part[(cp + RCH * r) * 8 + j];
            pooled[(size_t)b0 * H2 + tid] = s * (1.0f / 281.0f);
        }
    }
}

// ---------------- head kernels ----------------

__global__ void head1_k(const float* __restrict__ pooled, const float* __restrict__ emb,
                        const int* __restrict__ sidx, const float* __restrict__ w1,
                        const float* __restrict__ b1, float* __restrict__ hout) {
    int idx = blockIdx.x * 256 + threadIdx.x;
    if (idx >= Bz * H1) return;
    int b = idx >> 7, j = idx & 127;
    const float* wr = w1 + (size_t)j * (H2 + ED);
    const float* pr = pooled + (size_t)b * H2;
    float a = b1[j];
    for (int i = 0; i < H2; ++i) a = fmaf(pr[i], wr[i], a);
    const float* er = emb + (size_t)sidx[b] * ED;
    #pragma unroll
    for (int e = 0; e < ED; ++e) a = fmaf(er[e], wr[H2 + e], a);
    hout[idx] = fmaxf(a, 0.f);
}

__global__ __launch_bounds__(256)
void head2_k(const float* __restrict__ h, const float* __restrict__ w2,
             const float* __restrict__ b2, float* __restrict__ out) {
    const int n0 = blockIdx.x * 64;
    const int b0 = blockIdx.y * 16;
    __shared__ float hs[16][128];
    __shared__ float w2s[64][129];
    const int tid = threadIdx.x;
    for (int idx = tid; idx < 16 * 128; idx += 256) {
        int bl = idx >> 7, j = idx & 127;
        hs[bl][j] = h[(size_t)(b0 + bl) * H1 + j];
    }
    for (int idx = tid; idx < 64 * 128; idx += 256) {
        int nl = idx >> 7, j = idx & 127;
        int n = n0 + nl;
        w2s[nl][j] = (n < NCLS) ? w2[(size_t)n * H1 + j] : 0.f;
    }
    __syncthreads();
    const int nl = tid & 63, bg = tid >> 6;
    float acc[4] = {0.f, 0.f, 0.f, 0.f};
    for (int j = 0; j < 128; ++j) {
        const float wv = w2s[nl][j];
        #pragma unroll
        for (int bb = 0; bb < 4; ++bb) acc[bb] = fmaf(wv, hs[bg * 4 + bb][j], acc[bb]);
    }
    const int n = n0 + nl;
    if (n < NCLS) {
        const float bv = b2[n];
        #pragma unroll
        for (int bb = 0; bb < 4; ++bb)
            out[(size_t)(b0 + bg * 4 + bb) * NCLS + n] = acc[bb] + bv;
    }
}

// ---------------- host launch ----------------

extern "C" void kernel_launch(void* const* d_in, const int* in_sizes, int n_in,
                              void* d_out, int out_size, void* d_ws, size_t ws_size,
                              hipStream_t stream) {
    const float* X      = (const float*)d_in[0];
    const int*   sidx   = (const int*)  d_in[1];
    const float* attn   = (const float*)d_in[2];
    const float* sa_w   = (const float*)d_in[3];
    const float* sa_b   = (const float*)d_in[4];
    const float* subj_w = (const float*)d_in[5];
    const float* subj_b = (const float*)d_in[6];
    const float* b1c1w = (const float*)d_in[7];  const float* b1c1b = (const float*)d_in[8];
    const float* b1c2w = (const float*)d_in[9];  const float* b1c2b = (const float*)d_in[10];
    const float* b1g1  = (const float*)d_in[11]; const float* b1be1 = (const float*)d_in[12];
    const float* b1g2  = (const float*)d_in[13]; const float* b1be2 = (const float*)d_in[14];
    const float* b2c1w = (const float*)d_in[15]; const float* b2c1b = (const float*)d_in[16];
    const float* b2c2w = (const float*)d_in[17]; const float* b2c2b = (const float*)d_in[18];
    const float* b2g1  = (const float*)d_in[19]; const float* b2be1 = (const float*)d_in[20];
    const float* b2g2  = (const float*)d_in[21]; const float* b2be2 = (const float*)d_in[22];
    const float* b2skw = (const float*)d_in[23]; const float* b2skb = (const float*)d_in[24];
    const float* b3c1w = (const float*)d_in[25]; const float* b3c1b = (const float*)d_in[26];
    const float* b3c2w = (const float*)d_in[27]; const float* b3c2b = (const float*)d_in[28];
    const float* b3g1  = (const float*)d_in[29]; const float* b3be1 = (const float*)d_in[30];
    const float* b3g2  = (const float*)d_in[31]; const float* b3be2 = (const float*)d_in[32];
    const float* emb   = (const float*)d_in[33];
    const float* hw1   = (const float*)d_in[34]; const float* hb1 = (const float*)d_in[35];
    const float* hw2   = (const float*)d_in[36]; const float* hb2 = (const float*)d_in[37];
    float* out = (float*)d_out;
    (void)in_sizes; (void)n_in; (void)out_size; (void)ws_size;

    char* wsp = (char*)d_ws;
    size_t off = 0;
    auto allocF = [&](size_t n) {
        float* p = (float*)(wsp + off);
        off += ((n * sizeof(float)) + 255) & ~(size_t)255;
        return p;
    };
    auto allocS = [&](size_t n) {
        short* p = (short*)(wsp + off);
        off += ((n * sizeof(short)) + 255) & ~(size_t)255;
        return p;
    };
    float* attnS   = allocF((size_t)C0 * C0);
    float* Mmat    = allocF((size_t)H1 * C0);
    float* biasS   = allocF((size_t)4 * H1);
    float* pooled  = allocF((size_t)Bz * H2);
    float* hbuf    = allocF((size_t)Bz * H1);
    short* wStageA = allocS((size_t)4 * 10 * 4 * 2 * 512);    // per-subj 40960 (NC=10)
    short* wp_b1c1 = allocS((size_t)4 * 3 * 4 * 2 * 512);
    short* wp_b1c2 = allocS((size_t)4 * 3 * 4 * 2 * 512);
    short* wp_skip = allocS((size_t)4 * 1 * 8 * 2 * 512);
    short* wp_b2c1 = allocS((size_t)4 * 3 * 8 * 2 * 512);
    short* wp_b2c2 = allocS((size_t)8 * 3 * 8 * 2 * 512);
    short* wp_b3c1 = allocS((size_t)8 * 3 * 8 * 2 * 512);
    short* wp_b3c2 = allocS((size_t)8 * 3 * 8 * 2 * 512);
    short* xT   = allocS((size_t)Bz * TR * CP0 + 64);   // +64 pad: unit 36..39 over-read guard
    short* bufP = allocS((size_t)Bz * TR * H1);
    short* bufQ = allocS((size_t)Bz * TR * H1);
    short* bufR = allocS((size_t)Bz * TR * H2);
    short* bufS = allocS((size_t)Bz * TR * H2);

    // ---- zero margin rows ----
    zrows_k<<<Bz, 256, 0, stream>>>(xT, CP0);
    zrows_k<<<Bz, 256, 0, stream>>>(bufP, H1);
    zrows_k<<<Bz, 256, 0, stream>>>(bufQ, H1);
    zrows_k<<<Bz, 256, 0, stream>>>(bufR, H2);
    zrows_k<<<Bz, 256, 0, stream>>>(bufS, H2);

    // ---- prep ----
    softmax_rows_k<<<C0, 256, 0, stream>>>(attn, attnS, C0);
    gemm_M_k<<<(H1 * C0 + 255) / 256, 256, 0, stream>>>(sa_w, attnS, Mmat);
    msubA_k<<<(4 * 40960 + 255) / 256, 256, 0, stream>>>(subj_w, Mmat, wStageA);
    biasS_k<<<2, 256, 0, stream>>>(subj_w, sa_b, subj_b, biasS);
    wfrag_k<<<(4*3*4*2*512 + 255) / 256, 256, 0, stream>>>(b1c1w, wp_b1c1, 128, 128, 3, 4);
    wfrag_k<<<(4*3*4*2*512 + 255) / 256, 256, 0, stream>>>(b1c2w, wp_b1c2, 128, 128, 3, 4);
    wfrag_k<<<(4*1*8*2*512 + 255) / 256, 256, 0, stream>>>(b2skw, wp_skip, 128, 256, 1, 4);
    wfrag_k<<<(4*3*8*2*512 + 255) / 256, 256, 0, stream>>>(b2c1w, wp_b2c1, 128, 256, 3, 4);
    wfrag_k<<<(8*3*8*2*512 + 255) / 256, 256, 0, stream>>>(b2c2w, wp_b2c2, 256, 256, 3, 8);
    wfrag_k<<<(8*3*8*2*512 + 255) / 256, 256, 0, stream>>>(b3c1w, wp_b3c1, 256, 256, 3, 8);
    wfrag_k<<<(8*3*8*2*512 + 255) / 256, 256, 0, stream>>>(b3c2w, wp_b3c2, 256, 256, 3, 8);
    xpose_k<<<dim3(9, 9, Bz), dim3(32, 8), 0, stream>>>(X, xT);

    // ---- conv stack: <K, NCC, O_BLK, NOW, NB, GELU, HASRES, POOL> ----
    // stageA: xT(288ch, NCC=10) -> P(128), per-subject weights (6 waves)
    convOV<1, 10, 128, 2, 1, false, false, false><<<Bz, 384, 0, stream>>>(
        xT, CP0, wStageA, biasS, nullptr, nullptr, nullptr, bufP, nullptr, sidx, 40960, 128);
    // block1: P -> Q (gelu+bn); Q (+res P) -> P in-place   (NB=2, 12 waves)
    convOV<3, 4, 128, 2, 2, true, false, false><<<Bz / 2, 768, 0, stream>>>(
        bufP, H1, wp_b1c1, b1c1b, b1g1, b1be1, nullptr, bufQ, nullptr, nullptr, 0, 0);
    convOV<3, 4, 128, 2, 2, true, true, false><<<Bz / 2, 768, 0, stream>>>(
        bufQ, H1, wp_b1c2, b1c2b, b1g2, b1be2, bufP, bufP, nullptr, nullptr, 0, 0);
    // block2: skip P->S; c1 P->R (both 76KB LDS -> 2 blocks/CU); c2 R(+res S)->S
    convOV<1, 4, 256, 4, 1, false, false, false><<<Bz, 768, 0, stream>>>(
        bufP, H1, wp_skip, b2skb, nullptr, nullptr, nullptr, bufS, nullptr, nullptr, 0, 0);
    convOV<3, 4, 256, 4, 1, true, false, false><<<Bz, 768, 0, stream>>>(
        bufP, H1, wp_b2c1, b2c1b, b2g1, b2be1, nullptr, bufR, nullptr, nullptr, 0, 0);
    convOV<3, 8, 256, 4, 1, true, true, false><<<Bz, 768, 0, stream>>>(
        bufR, H2, wp_b2c2, b2c2b, b2g2, b2be2, bufS, bufS, nullptr, nullptr, 0, 0);
    // block3: c1 S->R; c2 R(+res S) -> fused global-avg-pool (direct store)
    convOV<3, 8, 256, 4, 1, true, false, false><<<Bz, 768, 0, stream>>>(
        bufS, H2, wp_b3c1, b3c1b, b3g1, b3be1, nullptr, bufR, nullptr, nullptr, 0, 0);
    convOV<3, 8, 256, 4, 1, true, true, true><<<Bz, 768, 0, stream>>>(
        bufR, H2, wp_b3c2, b3c2b, b3g2, b3be2, bufS, nullptr, pooled, nullptr, 0, 0);

    // ---- head ----
    head1_k<<<(Bz * H1 + 255) / 256, 256, 0, stream>>>(pooled, emb, sidx, hw1, hb1, hbuf);
    head2_k<<<dim3((NCLS + 63) / 64, Bz / 16), 256, 0, stream>>>(hbuf, hw2, hb2, out);
}

// Round 11
// 1304.848 us; speedup vs baseline: 9.7284x; 1.2331x over previous
//
#include <hip/hip_runtime.h>
#include <hip/hip_bf16.h>
#include <math.h>

constexpr int Bz = 1024;
constexpr int C0 = 271;   // input channels
constexpr int CP0 = 288;  // padded to 9*32
constexpr int Tt = 281;   // time
constexpr int TR = 292;   // padded rows per batch: row = t+1; rows 0,282..291 zero
constexpr int H1 = 128;
constexpr int H2 = 256;
constexpr int NCLS = 1854;
constexpr int ED = 16;
constexpr float BN_INV = 0.9999950000374996f;  // 1/sqrt(1+1e-5)

typedef __attribute__((ext_vector_type(8))) short s16x8;
typedef __attribute__((ext_vector_type(16))) float f32x16;

// fast erf (Abramowitz-Stegun 7.1.26, |eps| < 1.5e-7) -- validated r7-r10, absmax unchanged
__device__ __forceinline__ float erf_fast(float x) {
    float ax = fabsf(x);
    float t = __builtin_amdgcn_rcpf(fmaf(0.3275911f, ax, 1.0f));
    float p = fmaf(1.061405429f, t, -1.453152027f);
    p = fmaf(p, t, 1.421413741f);
    p = fmaf(p, t, -0.284496736f);
    p = fmaf(p, t, 0.254829592f);
    float e = __expf(-ax * ax);
    float r = fmaf(-p * t, e, 1.0f);
    return copysignf(r, x);
}
__device__ __forceinline__ float gelu_f(float v) {
    return 0.5f * v * (1.0f + erf_fast(v * 0.7071067811865475f));
}
__device__ __forceinline__ float bf2f(short s) {
    return __builtin_bit_cast(float, ((unsigned int)(unsigned short)s) << 16);
}
__device__ __forceinline__ short f2bf(float f) {
    return __builtin_bit_cast(short, __float2bfloat16(f));
}

typedef unsigned int u32;
typedef const __attribute__((address_space(1))) u32 gu32;
typedef __attribute__((address_space(3))) u32 lu32;

// async global->LDS, 16B per lane; LDS dest = uniform base + lane*16
__device__ __forceinline__ void gl16(const void* g, void* l) {
    __builtin_amdgcn_global_load_lds((gu32*)(uintptr_t)g, (lu32*)(uintptr_t)l, 16, 0, 0);
}
template<int N> __device__ __forceinline__ void waitv() {
    asm volatile("s_waitcnt vmcnt(%0)" :: "i"(N) : "memory");
}
__device__ __forceinline__ void hard_barrier() {
    __builtin_amdgcn_s_barrier();
    __builtin_amdgcn_sched_barrier(0);
}

// ---------------- prep kernels ----------------

__global__ void zrows_k(short* base, int C) {
    const int b = blockIdx.x;
    const int n = 11 * (C / 8);
    for (int i = threadIdx.x; i < n; i += 256) {
        int ri = i / (C / 8), c8 = i - ri * (C / 8);
        int row = (ri == 0) ? 0 : 281 + ri;   // 0, 282..291
        *(int4*)(base + ((size_t)b * TR + row) * C + c8 * 8) = make_int4(0, 0, 0, 0);
    }
}

__global__ void softmax_rows_k(const float* __restrict__ a, float* __restrict__ o, int n) {
    __shared__ float red[256];
    const int row = blockIdx.x, tid = threadIdx.x;
    const float* r = a + (size_t)row * n;
    float m = -1e30f;
    for (int i = tid; i < n; i += 256) m = fmaxf(m, r[i]);
    red[tid] = m; __syncthreads();
    for (int s = 128; s > 0; s >>= 1) { if (tid < s) red[tid] = fmaxf(red[tid], red[tid + s]); __syncthreads(); }
    m = red[0]; __syncthreads();
    float acc = 0.f;
    for (int i = tid; i < n; i += 256) acc += expf(r[i] - m);
    red[tid] = acc; __syncthreads();
    for (int s = 128; s > 0; s >>= 1) { if (tid < s) red[tid] += red[tid + s]; __syncthreads(); }
    const float inv = 1.0f / red[0];
    for (int i = tid; i < n; i += 256) o[(size_t)row * n + i] = expf(r[i] - m) * inv;
}

// M[o][c] = sum_i sa_w[o][i] * attnS[i][c]
__global__ void gemm_M_k(const float* __restrict__ sa_w, const float* __restrict__ attnS,
                         float* __restrict__ M) {
    int idx = blockIdx.x * 256 + threadIdx.x;
    if (idx >= H1 * C0) return;
    int o = idx / C0, c = idx - o * C0;
    float s = 0.f;
    for (int i = 0; i < C0; ++i) s = fmaf(sa_w[(size_t)o * C0 + i], attnS[(size_t)i * C0 + c], s);
    M[idx] = s;
}

// fragment-order weights: chunk r=((cc*K+k)*OB32+ob), kk; lane holds o=ob*32+(l&31),
// c = cc*32 + kk*16 + (l>>5)*8 + j
__global__ void wfrag_k(const float* __restrict__ w, short* __restrict__ out,
                        int CIN, int O, int K, int NC) {
    int idx = blockIdx.x * 256 + threadIdx.x;
    int OB32 = O / 32;
    int total = NC * K * OB32 * 2 * 512;
    if (idx >= total) return;
    int j = idx & 7, lane = (idx >> 3) & 63, kk = (idx >> 9) & 1, r = idx >> 10;
    int ob = r % OB32, r2 = r / OB32;
    int k = r2 % K, cc = r2 / K;
    int o = ob * 32 + (lane & 31);
    int c = cc * 32 + kk * 16 + (lane >> 5) * 8 + j;
    float v = (c < CIN) ? w[((size_t)o * CIN + c) * K + k] : 0.f;
    out[idx] = f2bf(v);
}

// stage-A fused weights in fragment order, per subject: val = sum_h subj_w[s][o][h] * M[h][c]
__global__ void msubA_k(const float* __restrict__ subj_w, const float* __restrict__ M,
                        short* __restrict__ out) {
    int idx = blockIdx.x * 256 + threadIdx.x;
    const int per_s = 9 * 1 * 4 * 2 * 512;   // NC=9,K=1,OB32=4
    if (idx >= 4 * per_s) return;
    int s = idx / per_s, rem = idx % per_s;
    int j = rem & 7, lane = (rem >> 3) & 63, kk = (rem >> 9) & 1, r = rem >> 10;
    int ob = r % 4, cc = r / 4;               // K=1
    int o = ob * 32 + (lane & 31);
    int c = cc * 32 + kk * 16 + (lane >> 5) * 8 + j;
    float a = 0.f;
    if (c < C0) {
        const float* wr = subj_w + ((size_t)s * 128 + o) * 128;
        for (int h = 0; h < 128; ++h) a = fmaf(wr[h], M[(size_t)h * C0 + c], a);
    }
    out[idx] = f2bf(a);
}

__global__ void biasS_k(const float* __restrict__ subj_w, const float* __restrict__ sa_b,
                        const float* __restrict__ subj_b, float* __restrict__ biasS) {
    int idx = blockIdx.x * 256 + threadIdx.x;
    if (idx >= 4 * H1) return;
    int s = idx >> 7, o = idx & 127;
    const float* wr = subj_w + ((size_t)s * H1 + o) * H1;
    float a = subj_b[idx];
    for (int h = 0; h < H1; ++h) a = fmaf(wr[h], sa_b[h], a);
    biasS[idx] = a;
}

// X [b][c][t] fp32 -> xT [b][row=t+1][288] bf16
__global__ void xpose_k(const float* __restrict__ X, short* __restrict__ xT) {
    __shared__ float tile[32][33];
    int b = blockIdx.z;
    int t0 = blockIdx.x * 32, c0 = blockIdx.y * 32;
    int tx = threadIdx.x, ty = threadIdx.y;
    #pragma unroll
    for (int i = 0; i < 4; ++i) {
        int c = c0 + ty + i * 8, t = t0 + tx;
        float v = 0.f;
        if (c < C0 && t < Tt) v = X[((size_t)b * C0 + c) * Tt + t];
        tile[ty + i * 8][tx] = v;
    }
    __syncthreads();
    #pragma unroll
    for (int i = 0; i < 4; ++i) {
        int t = t0 + ty + i * 8, c = c0 + tx;
        if (t < Tt) xT[((size_t)b * TR + t + 1) * CP0 + c] = f2bf(tile[tx][ty + i * 8]);
    }
}

// ---------------- main conv kernel: fragment-order MFMA, full-T blocks ----------------
// Block: NB batches x O_BLK outputs x full T. Waves: NB*NOW*3 (3 t-groups of 96).
// Double-buffered LDS staged purely by global_load_lds; counted vmcnt; 2 s_barrier/cc.
// POOL variant fuses the global average pool (bias/bn/res/gelu then reduce; no out write).

template<int K, int NC, int O_BLK, int NOW, int NB, bool GELU, bool HASRES, bool POOL>
__global__ __launch_bounds__(NOW * NB * 192)
void convMF(const short* __restrict__ xin, int XC,
            const short* __restrict__ wfrag,
            const float* __restrict__ bias,
            const float* __restrict__ gamma, const float* __restrict__ beta,
            const short* __restrict__ res, short* __restrict__ out,
            float* __restrict__ pooled,
            const int* __restrict__ sidx, int wsub, int bsub)
{
    constexpr int NW     = NOW * NB * 3;
    constexpr int NT     = NW * 64;
    constexpr int OB32   = O_BLK / 32;
    constexpr int PAD    = (K - 1) / 2;
    constexpr int RSTART = 1 - PAD;
    constexpr int A_I    = K * OB32 * 2;        // 1KB chunks per cc
    constexpr int X_I    = 18;                  // 288 rows * 64B / 1KB
    constexpr int TI     = A_I + NB * X_I;
    constexpr int Q      = TI / NW;
    constexpr int R      = TI % NW;
    constexpr int QH     = (R > 0) ? Q + 1 : Q;
    constexpr int ABYTES = A_I * 1024;
    constexpr int X_SLOT = X_I * 1024 + 256;    // slack rows for k-overhang reads
    constexpr int HALF   = ABYTES + NB * X_SLOT;
    constexpr int O2     = O_BLK * 2;

    __shared__ __align__(16) char smem[2 * HALF];

    const int b0   = blockIdx.x * NB;
    const int tid  = threadIdx.x;
    const int lane = tid & 63, wv = tid >> 6;
    const int l31  = lane & 31, hi = lane >> 5;
    const int bqw  = wv / (NOW * 3);
    const int w2   = wv % (NOW * 3);
    const int wvt  = w2 / NOW;          // t-group 0..2
    const int wvo  = w2 % NOW;          // o-group
    const int tg   = wvt * 96;
    const int Sw   = Q + (wv < R ? 1 : 0);

    int subj = sidx ? sidx[b0] : 0;
    const char*  wbase = (const char*)(wfrag + (size_t)subj * wsub);
    const float* bb    = bias + (size_t)subj * bsub;

    f32x16 acc[2][3];
    #pragma unroll
    for (int i = 0; i < 2; ++i)
        #pragma unroll
        for (int j = 0; j < 3; ++j)
            #pragma unroll
            for (int e = 0; e < 16; ++e) acc[i][j][e] = 0.f;

    auto issue = [&](int cc, int pb) {
        char* base = smem + pb * HALF;
        const char* wsrc = wbase + (size_t)cc * (A_I * 1024);
        for (int s = 0; s < Sw; ++s) {
            int i = s * NW + wv;
            if (i < A_I) {
                gl16(wsrc + (size_t)i * 1024 + lane * 16, base + i * 1024);
            } else {
                int xi = i - A_I;
                int bql = xi / X_I, seg = xi - bql * X_I;
                int q = seg * 64 + lane;
                int r = q >> 2, p = q & 3;
                int ps = p ^ ((r >> 1) & 3);
                const char* g = (const char*)xin +
                    (((size_t)(b0 + bql) * TR + (RSTART + r)) * XC + cc * 32) * 2 + ps * 16;
                gl16(g, base + ABYTES + bql * X_SLOT + seg * 1024);
            }
        }
    };

    issue(0, 0);
    int cur = 0;
    for (int cc = 0; cc < NC; ++cc) {
        if (cc + 1 < NC) {
            issue(cc + 1, cur ^ 1);
            if (wv < R) waitv<QH>(); else waitv<Q>();
        } else {
            waitv<0>();
        }
        hard_barrier();

        const char* Ab = smem + cur * HALF;
        const char* Xb = Ab + ABYTES + bqw * X_SLOT;
        #pragma unroll
        for (int k = 0; k < K; ++k) {
            #pragma unroll
            for (int kk = 0; kk < 2; ++kk) {
                s16x8 a0 = *(const s16x8*)(Ab + (((k * OB32 + wvo * 2 + 0) * 2 + kk) << 10) + (lane << 4));
                s16x8 a1 = *(const s16x8*)(Ab + (((k * OB32 + wvo * 2 + 1) * 2 + kk) << 10) + (lane << 4));
                #pragma unroll
                for (int ts = 0; ts < 3; ++ts) {
                    int rl = tg + ts * 32 + l31 + k;
                    s16x8 bv = *(const s16x8*)(Xb + rl * 64 + ((((kk << 1) | hi) ^ ((rl >> 1) & 3)) << 4));
                    acc[0][ts] = __builtin_amdgcn_mfma_f32_32x32x16_bf16(a0, bv, acc[0][ts], 0, 0, 0);
                    acc[1][ts] = __builtin_amdgcn_mfma_f32_32x32x16_bf16(a1, bv, acc[1][ts], 0, 0, 0);
                }
            }
        }
        hard_barrier();
        cur ^= 1;
    }

    // ---------------- epilogue: 3 t-sections through LDS ----------------
    constexpr int RCH = O_BLK / 8;
    float ps[8];
    if constexpr (POOL) {
        #pragma unroll
        for (int j = 0; j < 8; ++j) ps[j] = 0.f;
    }
    for (int g = 0; g < 3; ++g) {
        __syncthreads();
        if (wvt == g) {
            #pragma unroll
            for (int os = 0; os < 2; ++os) {
                #pragma unroll
                for (int rq = 0; rq < 4; ++rq) {
                    #pragma unroll
                    for (int rp = 0; rp < 2; ++rp) {
                        const int oc = wvo * 64 + os * 32 + 8 * rq + rp * 2 + 4 * hi;
                        const float bv0 = bb[oc], bv1 = bb[oc + 1];
                        const float g0 = gamma ? gamma[oc] * BN_INV : 1.f;
                        const float g1 = gamma ? gamma[oc + 1] * BN_INV : 1.f;
                        const float e0 = beta ? beta[oc] : 0.f;
                        const float e1 = beta ? beta[oc + 1] : 0.f;
                        const int r0 = rq * 4 + rp * 2;
                        #pragma unroll
                        for (int ts = 0; ts < 3; ++ts) {
                            float v0 = (acc[os][ts][r0] + bv0) * g0 + e0;
                            float v1 = (acc[os][ts][r0 + 1] + bv1) * g1 + e1;
                            int tl = ts * 32 + l31;
                            int byte = (bqw * 96 + tl) * O2 + ((oc * 2) ^ ((tl & 15) << 4));
                            __hip_bfloat162 pk;
                            pk.x = __float2bfloat16(v0);
                            pk.y = __float2bfloat16(v1);
                            *(__hip_bfloat162*)(smem + byte) = pk;
                        }
                    }
                }
            }
        }
        __syncthreads();
        for (int qq = tid; qq < NB * 96 * RCH; qq += NT) {
            int bql = qq / (96 * RCH), rem = qq - bql * (96 * RCH);
            int r = rem / RCH, cp = rem - r * RCH;
            int t = g * 96 + r;
            if (t >= Tt) continue;
            s16x8 hv = *(const s16x8*)(smem + (bql * 96 + r) * O2 + ((cp * 16) ^ ((r & 15) << 4)));
            size_t orow = ((size_t)(b0 + bql) * TR + t + 1) * O_BLK + cp * 8;
            s16x8 rv;
            if (HASRES) rv = *(const s16x8*)(res + orow);
            if constexpr (POOL) {
                #pragma unroll
                for (int j = 0; j < 8; ++j) {
                    float v = bf2f(hv[j]);
                    if (HASRES) v += bf2f(rv[j]);
                    if (GELU) v = gelu_f(v);
                    ps[j] += v;
                }
            } else {
                s16x8 ov;
                #pragma unroll
                for (int j = 0; j < 8; ++j) {
                    float v = bf2f(hv[j]);
                    if (HASRES) v += bf2f(rv[j]);
                    if (GELU) v = gelu_f(v);
                    ov[j] = f2bf(v);
                }
                *(s16x8*)(out + orow) = ov;
            }
        }
    }

    if constexpr (POOL) {
        // per-thread ps[] covers fixed 8-channel slice cp = tid % RCH (NT % RCH == 0):
        // LDS partial reduce, direct store (full-T block, NB=1 -> no atomics)
        constexpr int NRED = NT / RCH;
        float* part = (float*)smem;
        __syncthreads();
        #pragma unroll
        for (int j = 0; j < 8; ++j) part[tid * 8 + j] = ps[j];
        __syncthreads();
        if (tid < O_BLK) {
            int cp = tid >> 3, j = tid & 7;
            float s = 0.f;
            for (int r = 0; r < NRED; ++r) s += part[(cp + RCH * r) * 8 + j];
            pooled[(size_t)b0 * H2 + tid] = s * (1.0f / 281.0f);
        }
    }
}

// ---------------- head kernels ----------------

__global__ void head1_k(const float* __restrict__ pooled, const float* __restrict__ emb,
                        const int* __restrict__ sidx, const float* __restrict__ w1,
                        const float* __restrict__ b1, float* __restrict__ hout) {
    int idx = blockIdx.x * 256 + threadIdx.x;
    if (idx >= Bz * H1) return;
    int b = idx >> 7, j = idx & 127;
    const float* wr = w1 + (size_t)j * (H2 + ED);
    const float* pr = pooled + (size_t)b * H2;
    float a = b1[j];
    for (int i = 0; i < H2; ++i) a = fmaf(pr[i], wr[i], a);
    const float* er = emb + (size_t)sidx[b] * ED;
    #pragma unroll
    for (int e = 0; e < ED; ++e) a = fmaf(er[e], wr[H2 + e], a);
    hout[idx] = fmaxf(a, 0.f);
}

__global__ __launch_bounds__(256)
void head2_k(const float* __restrict__ h, const float* __restrict__ w2,
             const float* __restrict__ b2, float* __restrict__ out) {
    const int n0 = blockIdx.x * 64;
    const int b0 = blockIdx.y * 16;
    __shared__ float hs[16][128];
    __shared__ float w2s[64][129];
    const int tid = threadIdx.x;
    for (int idx = tid; idx < 16 * 128; idx += 256) {
        int bl = idx >> 7, j = idx & 127;
        hs[bl][j] = h[(size_t)(b0 + bl) * H1 + j];
    }
    for (int idx = tid; idx < 64 * 128; idx += 256) {
        int nl = idx >> 7, j = idx & 127;
        int n = n0 + nl;
        w2s[nl][j] = (n < NCLS) ? w2[(size_t)n * H1 + j] : 0.f;
    }
    __syncthreads();
    const int nl = tid & 63, bg = tid >> 6;
    float acc[4] = {0.f, 0.f, 0.f, 0.f};
    for (int j = 0; j < 128; ++j) {
        const float wv = w2s[nl][j];
        #pragma unroll
        for (int bb = 0; bb < 4; ++bb) acc[bb] = fmaf(wv, hs[bg * 4 + bb][j], acc[bb]);
    }
    const int n = n0 + nl;
    if (n < NCLS) {
        const float bv = b2[n];
        #pragma unroll
        for (int bb = 0; bb < 4; ++bb)
            out[(size_t)(b0 + bg * 4 + bb) * NCLS + n] = acc[bb] + bv;
    }
}

// ---------------- host launch ----------------

extern "C" void kernel_launch(void* const* d_in, const int* in_sizes, int n_in,
                              void* d_out, int out_size, void* d_ws, size_t ws_size,
                              hipStream_t stream) {
    const float* X      = (const float*)d_in[0];
    const int*   sidx   = (const int*)  d_in[1];
    const float* attn   = (const float*)d_in[2];
    const float* sa_w   = (const float*)d_in[3];
    const float* sa_b   = (const float*)d_in[4];
    const float* subj_w = (const float*)d_in[5];
    const float* subj_b = (const float*)d_in[6];
    const float* b1c1w = (const float*)d_in[7];  const float* b1c1b = (const float*)d_in[8];
    const float* b1c2w = (const float*)d_in[9];  const float* b1c2b = (const float*)d_in[10];
    const float* b1g1  = (const float*)d_in[11]; const float* b1be1 = (const float*)d_in[12];
    const float* b1g2  = (const float*)d_in[13]; const float* b1be2 = (const float*)d_in[14];
    const float* b2c1w = (const float*)d_in[15]; const float* b2c1b = (const float*)d_in[16];
    const float* b2c2w = (const float*)d_in[17]; const float* b2c2b = (const float*)d_in[18];
    const float* b2g1  = (const float*)d_in[19]; const float* b2be1 = (const float*)d_in[20];
    const float* b2g2  = (const float*)d_in[21]; const float* b2be2 = (const float*)d_in[22];
    const float* b2skw = (const float*)d_in[23]; const float* b2skb = (const float*)d_in[24];
    const float* b3c1w = (const float*)d_in[25]; const float* b3c1b = (const float*)d_in[26];
    const float* b3c2w = (const float*)d_in[27]; const float* b3c2b = (const float*)d_in[28];
    const float* b3g1  = (const float*)d_in[29]; const float* b3be1 = (const float*)d_in[30];
    const float* b3g2  = (const float*)d_in[31]; const float* b3be2 = (const float*)d_in[32];
    const float* emb   = (const float*)d_in[33];
    const float* hw1   = (const float*)d_in[34]; const float* hb1 = (const float*)d_in[35];
    const float* hw2   = (const float*)d_in[36]; const float* hb2 = (const float*)d_in[37];
    float* out = (float*)d_out;
    (void)in_sizes; (void)n_in; (void)out_size; (void)ws_size;

    char* wsp = (char*)d_ws;
    size_t off = 0;
    auto allocF = [&](size_t n) {
        float* p = (float*)(wsp + off);
        off += ((n * sizeof(float)) + 255) & ~(size_t)255;
        return p;
    };
    auto allocS = [&](size_t n) {
        short* p = (short*)(wsp + off);
        off += ((n * sizeof(short)) + 255) & ~(size_t)255;
        return p;
    };
    float* attnS   = allocF((size_t)C0 * C0);
    float* Mmat    = allocF((size_t)H1 * C0);
    float* biasS   = allocF((size_t)4 * H1);
    float* pooled  = allocF((size_t)Bz * H2);
    float* hbuf    = allocF((size_t)Bz * H1);
    short* wStageA = allocS((size_t)4 * 9 * 4 * 2 * 512);     // per-subj 36864
    short* wp_b1c1 = allocS((size_t)4 * 3 * 4 * 2 * 512);
    short* wp_b1c2 = allocS((size_t)4 * 3 * 4 * 2 * 512);
    short* wp_skip = allocS((size_t)4 * 1 * 8 * 2 * 512);
    short* wp_b2c1 = allocS((size_t)4 * 3 * 8 * 2 * 512);
    short* wp_b2c2 = allocS((size_t)8 * 3 * 8 * 2 * 512);
    short* wp_b3c1 = allocS((size_t)8 * 3 * 8 * 2 * 512);
    short* wp_b3c2 = allocS((size_t)8 * 3 * 8 * 2 * 512);
    short* xT   = allocS((size_t)Bz * TR * CP0);
    short* bufP = allocS((size_t)Bz * TR * H1);
    short* bufQ = allocS((size_t)Bz * TR * H1);
    short* bufR = allocS((size_t)Bz * TR * H2);
    short* bufS = allocS((size_t)Bz * TR * H2);

    // ---- zero margin rows ----
    zrows_k<<<Bz, 256, 0, stream>>>(xT, CP0);
    zrows_k<<<Bz, 256, 0, stream>>>(bufP, H1);
    zrows_k<<<Bz, 256, 0, stream>>>(bufQ, H1);
    zrows_k<<<Bz, 256, 0, stream>>>(bufR, H2);
    zrows_k<<<Bz, 256, 0, stream>>>(bufS, H2);

    // ---- prep ----
    softmax_rows_k<<<C0, 256, 0, stream>>>(attn, attnS, C0);
    gemm_M_k<<<(H1 * C0 + 255) / 256, 256, 0, stream>>>(sa_w, attnS, Mmat);
    msubA_k<<<(4 * 36864 + 255) / 256, 256, 0, stream>>>(subj_w, Mmat, wStageA);
    biasS_k<<<2, 256, 0, stream>>>(subj_w, sa_b, subj_b, biasS);
    wfrag_k<<<(4*3*4*2*512 + 255) / 256, 256, 0, stream>>>(b1c1w, wp_b1c1, 128, 128, 3, 4);
    wfrag_k<<<(4*3*4*2*512 + 255) / 256, 256, 0, stream>>>(b1c2w, wp_b1c2, 128, 128, 3, 4);
    wfrag_k<<<(4*1*8*2*512 + 255) / 256, 256, 0, stream>>>(b2skw, wp_skip, 128, 256, 1, 4);
    wfrag_k<<<(4*3*8*2*512 + 255) / 256, 256, 0, stream>>>(b2c1w, wp_b2c1, 128, 256, 3, 4);
    wfrag_k<<<(8*3*8*2*512 + 255) / 256, 256, 0, stream>>>(b2c2w, wp_b2c2, 256, 256, 3, 8);
    wfrag_k<<<(8*3*8*2*512 + 255) / 256, 256, 0, stream>>>(b3c1w, wp_b3c1, 256, 256, 3, 8);
    wfrag_k<<<(8*3*8*2*512 + 255) / 256, 256, 0, stream>>>(b3c2w, wp_b3c2, 256, 256, 3, 8);
    xpose_k<<<dim3(9, 9, Bz), dim3(32, 8), 0, stream>>>(X, xT);

    // ---- conv stack: <K, NC, O_BLK, NOW, NB, GELU, HASRES, POOL> ----
    // stageA: xT(288) -> P(128), per-subject weights, bias only
    convMF<1, 9, 128, 2, 1, false, false, false><<<Bz, 384, 0, stream>>>(
        xT, CP0, wStageA, biasS, nullptr, nullptr, nullptr, bufP, nullptr, sidx, 36864, 128);
    // block1: P -> Q (gelu+bn); Q (+res P) -> P in-place
    convMF<3, 4, 128, 2, 2, true, false, false><<<Bz / 2, 768, 0, stream>>>(
        bufP, H1, wp_b1c1, b1c1b, b1g1, b1be1, nullptr, bufQ, nullptr, nullptr, 0, 0);
    convMF<3, 4, 128, 2, 2, true, true, false><<<Bz / 2, 768, 0, stream>>>(
        bufQ, H1, wp_b1c2, b1c2b, b1g2, b1be2, bufP, bufP, nullptr, nullptr, 0, 0);
    // block2: skip P->S; c1 P->R; c2 R(+res S)->S in-place
    convMF<1, 4, 256, 4, 1, false, false, false><<<Bz, 768, 0, stream>>>(
        bufP, H1, wp_skip, b2skb, nullptr, nullptr, nullptr, bufS, nullptr, nullptr, 0, 0);
    convMF<3, 4, 256, 4, 1, true, false, false><<<Bz, 768, 0, stream>>>(
        bufP, H1, wp_b2c1, b2c1b, b2g1, b2be1, nullptr, bufR, nullptr, nullptr, 0, 0);
    convMF<3, 8, 256, 4, 1, true, true, false><<<Bz, 768, 0, stream>>>(
        bufR, H2, wp_b2c2, b2c2b, b2g2, b2be2, bufS, bufS, nullptr, nullptr, 0, 0);
    // block3: c1 S->R; c2 R(+res S) -> fused global-avg-pool (direct store, no out write)
    convMF<3, 8, 256, 4, 1, true, false, false><<<Bz, 768, 0, stream>>>(
        bufS, H2, wp_b3c1, b3c1b, b3g1, b3be1, nullptr, bufR, nullptr, nullptr, 0, 0);
    convMF<3, 8, 256, 4, 1, true, true, true><<<Bz, 768, 0, stream>>>(
        bufR, H2, wp_b3c2, b3c2b, b3g2, b3be2, bufS, nullptr, pooled, nullptr, 0, 0);

    // ---- head ----
    head1_k<<<(Bz * H1 + 255) / 256, 256, 0, stream>>>(pooled, emb, sidx, hw1, hb1, hbuf);
    head2_k<<<dim3((NCLS + 63) / 64, Bz / 16), 256, 0, stream>>>(hbuf, hw2, hb2, out);
}